// Round 6
// baseline (698.794 us; speedup 1.0000x reference)
//
#include <hip/hip_runtime.h>

typedef _Float16 f16;
typedef __attribute__((ext_vector_type(8))) _Float16 f16x8;
typedef __attribute__((ext_vector_type(4))) float floatx4;
typedef __attribute__((ext_vector_type(16))) float floatx16;

union H8 { f16 h[8]; uint4 v; };

#if defined(__has_builtin)
#if __has_builtin(__builtin_elementwise_max)
#define HAVE_EMAX 1
#endif
#endif

__device__ __forceinline__ f16x8 relu8(f16x8 x) {
    f16x8 z = {};
#ifdef HAVE_EMAX
    return __builtin_elementwise_max(x, z);
#else
    f16x8 r;
#pragma unroll
    for (int j = 0; j < 8; j++) r[j] = x[j] > (f16)0 ? x[j] : (f16)0;
    return r;
#endif
}

// ---------------- P0 (fused): weight prep (fp16 frag tables) + x0/u1/u2 ----------------
// Blocks 0..15: W2f in 32x32x16 B-frag order:
//   W2f[k][step<16][ctg<8][lane<64][j<8] = W2[k][kk=step*16+(lane>>5)*8+j][n=ctg*32+(lane&31)]
// Blocks 16..32: Wo1f/Wo2f in 16x16x32 B-frag order (as before). Block 33: Wo3f.
// Blocks 34..289: compute_u (u1 in 32x32 A-frag order, u2 row order).
__global__ void prep_and_u(const float* __restrict__ Wm2, const float* __restrict__ Wo1,
                           const float* __restrict__ Wo2, const float* __restrict__ Wo3,
                           f16* __restrict__ W2f, f16* __restrict__ Wo1f,
                           f16* __restrict__ Wo2f, f16* __restrict__ Wo3f,
                           const float* __restrict__ data, const float* __restrict__ act,
                           const float* __restrict__ Wm1, const float* __restrict__ bm1,
                           float* __restrict__ x0, f16* __restrict__ u1f, f16* __restrict__ u2) {
    __shared__ float tile[32 * 257];
    __shared__ float t3[256 * 25];
    int id = blockIdx.x;
    int tid = threadIdx.x;
    if (id < 16) {
        // W2 -> 32x32x16 B-frag table
        int k = id >> 3, s = id & 7;               // s = 32-row K chunk
        const float* src = Wm2 + k * 65536;
        int kk0 = s * 32;
        for (int t = tid; t < 32 * 256; t += 256) {
            int r = t >> 8, c = t & 255;
            tile[r * 257 + c] = src[(size_t)(kk0 + r) * 256 + c];
        }
        __syncthreads();
#pragma unroll
        for (int it = 0; it < 4; it++) {
            int t = tid + 256 * it;                // 0..1023 = (ls, ctg, l)
            int ls = t >> 9, ctg = (t >> 6) & 7, l = t & 63;
            int n = ctg * 32 + (l & 31);
            int kkl = ls * 16 + ((l >> 5) & 1) * 8;
            H8 o;
#pragma unroll
            for (int j = 0; j < 8; j++) o.h[j] = (f16)tile[(kkl + j) * 257 + n];
            *(uint4*)(W2f + (size_t)k * 131072 + ((size_t)((s * 2 + ls) * 8 + ctg)) * 512 + l * 8) = o.v;
        }
    } else if (id < 33) {
        const float* src; f16* dst; int s, Ksrc;
        if (id < 25) { s = id - 16; src = Wo1; dst = Wo1f; Ksrc = 280; }
        else         { s = id - 25; src = Wo2; dst = Wo2f; Ksrc = 256; }
        int kk0 = s * 32;
        for (int t = tid; t < 32 * 256; t += 256) {
            int r = t >> 8, c = t & 255;
            tile[r * 257 + c] = (kk0 + r < Ksrc) ? src[(size_t)(kk0 + r) * 256 + c] : 0.f;
        }
        __syncthreads();
#pragma unroll
        for (int it = 0; it < 4; it++) {
            int t = tid + 256 * it;                // (nt, l) for 16x16x32 frags
            int nt = t >> 6, l = t & 63;
            int n = nt * 16 + (l & 15), q = l >> 4;
            H8 o;
#pragma unroll
            for (int j = 0; j < 8; j++) o.h[j] = (f16)tile[(q * 8 + j) * 257 + n];
            *(uint4*)(dst + ((size_t)(s * 16 + nt)) * 512 + l * 8) = o.v;
        }
    } else if (id == 33) {
        for (int t = tid; t < 256 * 24; t += 256) {
            int r = t / 24, c = t - r * 24;
            t3[r * 25 + c] = Wo3[t];
        }
        __syncthreads();
#pragma unroll
        for (int it = 0; it < 4; it++) {
            int e = tid + 256 * it;
            int s3 = e >> 7, nt = (e >> 6) & 1, l = e & 63;
            int n = nt * 16 + (l & 15), q = l >> 4;
            H8 o;
#pragma unroll
            for (int j = 0; j < 8; j++) {
                int kk = s3 * 32 + q * 8 + j;
                o.h[j] = (f16)((n < 24) ? t3[kk * 25 + n] : 0.f);
            }
            *(uint4*)(Wo3f + (size_t)e * 8) = o.v;
        }
    } else {
        // ---- compute_u: u1[b,n,k,h] = x0·W1[k][0:24,h]; u2 = x0·W1[k][24:48,h]+b1 ----
        int r0 = (id - 34) * 16;
        int b = r0 >> 6;
        float* xs = tile;
        for (int idx = tid; idx < 16 * 24; idx += 256) {
            int rr = idx / 24, d = idx - rr * 24;
            int r = r0 + rr;
            float v = (d < 16) ? data[(r * 2) * 16 + d]       // t=0 only (output keeps t=0)
                               : act[(r * 2) * 8 + (d - 16)];
            xs[rr * 24 + d] = v;
            x0[r * 24 + d] = v;
        }
        __syncthreads();
        int h = tid;
        float acc[4][16];
#pragma unroll
        for (int q = 0; q < 4; q++)
#pragma unroll
            for (int rr = 0; rr < 16; rr++) acc[q][rr] = 0.f;
#pragma unroll
        for (int d = 0; d < 24; d++) {
            float w10 = Wm1[(0 * 48 + d) * 256 + h];
            float w11 = Wm1[(1 * 48 + d) * 256 + h];
            float w20 = Wm1[(0 * 48 + 24 + d) * 256 + h];
            float w21 = Wm1[(1 * 48 + 24 + d) * 256 + h];
#pragma unroll
            for (int rr = 0; rr < 16; rr++) {
                float x = xs[rr * 24 + d];
                acc[0][rr] += x * w10;
                acc[1][rr] += x * w11;
                acc[2][rr] += x * w20;
                acc[3][rr] += x * w21;
            }
        }
        float bb0 = bm1[h], bb1 = bm1[256 + h];
        // u1f: 32x32 A-frag order: entry = (step*2+rt)*64 + lane, j
        int step = h >> 4, j = h & 7, lanehalf = (h >> 3) & 1;
#pragma unroll
        for (int rr = 0; rr < 16; rr++) {
            int r = r0 + rr;
            int row = r & 63;
            int entry = (step * 2 + (row >> 5)) * 64 + ((row & 31) | (lanehalf << 5));
            u1f[((size_t)(b * 2 + 0)) * 16384 + entry * 8 + j] = (f16)acc[0][rr];
            u1f[((size_t)(b * 2 + 1)) * 16384 + entry * 8 + j] = (f16)acc[1][rr];
            u2[((size_t)r * 2 + 0) * 256 + h] = (f16)(acc[2][rr] + bb0);
            u2[((size_t)r * 2 + 1) * 256 + h] = (f16)(acc[3][rr] + bb1);
        }
    }
}

// ---------------- K3: edge MLP layer-2 + weighted aggregate ----------------
// block = (b, 4 receivers). u1 frags staged in LDS once per k (shared by 4 i's);
// i-loop is barrier-free: A built in regs (2 ds_read + broadcast u2 + pk add/relu),
// B frags streamed from L2 per step. 32x32x16 MFMA, bias folded into acc init.
__global__ __launch_bounds__(256, 4) void edge_kernel(
    const f16* __restrict__ u1f, const f16* __restrict__ u2, const float* __restrict__ edges,
    const f16* __restrict__ W2f, const float* __restrict__ bm2, float* __restrict__ agg) {
    int blk = blockIdx.x;
    int b = blk >> 4;
    int i0 = (blk & 15) * 4;
    __shared__ __align__(16) f16 u1s[16384];      // 32 KB: [step<16][rt<2][lane<64][8]
    __shared__ __align__(16) f16 u2s[4 * 256];    // 2 KB
    __shared__ float w_s[4 * 64];                 // 1 KB
    __shared__ float aggs[4 * 256];               // 4 KB   (total 39.9 KB -> 4 blocks/CU)
    int tid = threadIdx.x;
    int lane = tid & 63, wave = tid >> 6;
    const int l5 = lane >> 5;                     // 0/1: K-half
    const int colBase = wave * 64;

#pragma unroll
    for (int t = tid; t < 1024; t += 256) aggs[t] = 0.f;

#pragma unroll 1
    for (int k = 0; k < 2; k++) {
        __syncthreads();                          // waves done with u1s/u2s of prev k
        {   // stage u1 frags (32 KB, straight copy in frag order)
            const uint4* src = (const uint4*)(u1f + ((size_t)(b * 2 + k)) * 16384);
            uint4* dst = (uint4*)u1s;
#pragma unroll
            for (int it = 0; it < 8; it++) dst[tid + 256 * it] = src[tid + 256 * it];
        }
        if (tid < 128) {                          // stage u2 rows (4 x 256 f16)
            int ii = tid >> 5, u4 = tid & 31;
            *(uint4*)&u2s[ii * 256 + u4 * 8] =
                *(const uint4*)&u2[((size_t)(b * 64 + i0 + ii) * 2 + k) * 256 + u4 * 8];
        }
        {   // stage edge weights (4 x 64)
            int ii = tid >> 6, j = tid & 63;
            int ia = i0 + ii;
            float w = 0.f;
            if (j != ia) {
                int jj = j - (j > ia ? 1 : 0);
                w = edges[((size_t)b * 4032 + (size_t)ia * 63 + jj) * 2 + k];
            }
            w_s[tid] = w;
        }
        float bb[2];
#pragma unroll
        for (int ct = 0; ct < 2; ct++) bb[ct] = bm2[k * 256 + colBase + ct * 32 + (lane & 31)];
        __syncthreads();

        const f16* Wkb = W2f + (size_t)k * 131072 + (size_t)(wave * 2) * 512 + lane * 8;

#pragma unroll 1
        for (int il = 0; il < 4; il++) {
            floatx16 acc[2][2];                   // [rt][ct], bias pre-folded
#pragma unroll
            for (int rt = 0; rt < 2; rt++)
#pragma unroll
                for (int ct = 0; ct < 2; ct++)
#pragma unroll
                    for (int q = 0; q < 16; q++) acc[rt][ct][q] = bb[ct];

            const f16* pu2 = &u2s[il * 256 + l5 * 8];
#pragma unroll
            for (int step = 0; step < 16; step++) {
                f16x8 bfr[2];
#pragma unroll
                for (int ct = 0; ct < 2; ct++)
                    bfr[ct] = *(const f16x8*)(Wkb + (size_t)(step * 8 + ct) * 512);
                f16x8 uv = *(const f16x8*)(pu2 + step * 16);
                f16x8 af[2];
#pragma unroll
                for (int rt = 0; rt < 2; rt++) {
                    f16x8 u1v = *(const f16x8*)&u1s[((step * 2 + rt) * 64 + lane) * 8];
                    af[rt] = relu8(u1v + uv);
                }
#pragma unroll
                for (int rt = 0; rt < 2; rt++)
#pragma unroll
                    for (int ct = 0; ct < 2; ct++)
                        acc[rt][ct] = __builtin_amdgcn_mfma_f32_32x32x16_f16(
                            af[rt], bfr[ct], acc[rt][ct], 0, 0, 0);
            }
            // epilogue: sum_j relu(C)*w.  C: col=lane&31, row=(reg&3)+8*(reg>>2)+4*(lane>>5)
#pragma unroll
            for (int ct = 0; ct < 2; ct++) {
                float p = 0.f;
#pragma unroll
                for (int rt = 0; rt < 2; rt++) {
                    const float* wr = &w_s[il * 64 + rt * 32 + l5 * 4];
#pragma unroll
                    for (int g = 0; g < 4; g++) {
                        float4 wv = *(const float4*)(wr + g * 8);
                        p += fmaxf(acc[rt][ct][g * 4 + 0], 0.f) * wv.x;
                        p += fmaxf(acc[rt][ct][g * 4 + 1], 0.f) * wv.y;
                        p += fmaxf(acc[rt][ct][g * 4 + 2], 0.f) * wv.z;
                        p += fmaxf(acc[rt][ct][g * 4 + 3], 0.f) * wv.w;
                    }
                }
                p += __shfl_xor(p, 32, 64);
                if (l5 == 0) aggs[il * 256 + colBase + ct * 32 + lane] += p;  // wave-private cols
            }
        }
    }
    __syncthreads();
#pragma unroll
    for (int t = tid; t < 1024; t += 256)
        agg[((size_t)(b * 64 + i0 + (t >> 8))) * 256 + (t & 255)] = aggs[t];
}

// ---------------- K4: out-MLP, 4 blocks per batch (M=16 rows each) ----------------
__global__ void out_mlp(const float* __restrict__ x0, const float* __restrict__ agg,
                        const f16* __restrict__ Wo1f, const f16* __restrict__ Wo2f,
                        const f16* __restrict__ Wo3f,
                        const float* __restrict__ bo1, const float* __restrict__ bo2,
                        const float* __restrict__ bo3,
                        const float* __restrict__ Wq2, const float* __restrict__ bq2,
                        const float* __restrict__ Wq3, const float* __restrict__ bq3,
                        float* __restrict__ out) {
    int blk = blockIdx.x;
    int b = blk >> 2, n0 = (blk & 3) * 16;
    int tid = threadIdx.x;
    int lane = tid & 63, wave = tid >> 6;
    const int colBase = wave * 64;
    const int lhi = lane >> 4;
    __shared__ __align__(16) f16 A1f[9 * 64 * 8];
    __shared__ __align__(16) f16 A2f[8 * 64 * 8];
    __shared__ __align__(16) f16 h2f[8 * 64 * 8];
    __shared__ float pq[16][2];

    for (int t = tid; t < 576; t += 256) {
        int lane_f = t & 63, s = t >> 6;
        int m = n0 + (lane_f & 15);
        int c0 = s * 32 + (lane_f >> 4) * 8;
        float vals[8];
        if (c0 < 24) {
            const float4* xr = (const float4*)(x0 + (b * 64 + m) * 24 + c0);
            float4 a = xr[0], c = xr[1];
            vals[0] = a.x; vals[1] = a.y; vals[2] = a.z; vals[3] = a.w;
            vals[4] = c.x; vals[5] = c.y; vals[6] = c.z; vals[7] = c.w;
        } else if (c0 < 280) {
            const float4* ar = (const float4*)(agg + ((size_t)(b * 64 + m)) * 256 + (c0 - 24));
            float4 a = ar[0], c = ar[1];
            vals[0] = a.x; vals[1] = a.y; vals[2] = a.z; vals[3] = a.w;
            vals[4] = c.x; vals[5] = c.y; vals[6] = c.z; vals[7] = c.w;
        } else {
#pragma unroll
            for (int q = 0; q < 8; q++) vals[q] = 0.f;
        }
        H8 o;
#pragma unroll
        for (int q = 0; q < 8; q++) o.h[q] = (f16)vals[q];
        *(uint4*)(&A1f[t * 8]) = o.v;
    }
    __syncthreads();

    floatx4 acc[4];
#pragma unroll
    for (int ct = 0; ct < 4; ct++)
#pragma unroll
        for (int q = 0; q < 4; q++) acc[ct][q] = 0.f;
#pragma unroll
    for (int step = 0; step < 9; step++) {
        f16x8 af = *(const f16x8*)(&A1f[(step * 64 + lane) * 8]);
#pragma unroll
        for (int ct = 0; ct < 4; ct++) {
            f16x8 bfr = *(const f16x8*)(Wo1f + ((size_t)(step * 16 + wave * 4 + ct)) * 512 + lane * 8);
            acc[ct] = __builtin_amdgcn_mfma_f32_16x16x32_f16(af, bfr, acc[ct], 0, 0, 0);
        }
    }
#pragma unroll
    for (int ct = 0; ct < 4; ct++) {
        int col = colBase + ct * 16 + (lane & 15);
        float bbv = bo1[col];
        int s2 = col >> 5, jj = col & 7, lf_hi = ((col >> 3) & 3) << 4;
#pragma unroll
        for (int reg = 0; reg < 4; reg++) {
            int row = lhi * 4 + reg;
            A2f[(s2 * 64 + (row | lf_hi)) * 8 + jj] = (f16)fmaxf(acc[ct][reg] + bbv, 0.f);
        }
    }
    __syncthreads();

#pragma unroll
    for (int ct = 0; ct < 4; ct++)
#pragma unroll
        for (int q = 0; q < 4; q++) acc[ct][q] = 0.f;
#pragma unroll
    for (int step = 0; step < 8; step++) {
        f16x8 af = *(const f16x8*)(&A2f[(step * 64 + lane) * 8]);
#pragma unroll
        for (int ct = 0; ct < 4; ct++) {
            f16x8 bfr = *(const f16x8*)(Wo2f + ((size_t)(step * 16 + wave * 4 + ct)) * 512 + lane * 8);
            acc[ct] = __builtin_amdgcn_mfma_f32_16x16x32_f16(af, bfr, acc[ct], 0, 0, 0);
        }
    }
#pragma unroll
    for (int ct = 0; ct < 4; ct++) {
        int col = colBase + ct * 16 + (lane & 15);
        float bbv = bo2[col];
        int s2 = col >> 5, jj = col & 7, lf_hi = ((col >> 3) & 3) << 4;
#pragma unroll
        for (int reg = 0; reg < 4; reg++) {
            int row = lhi * 4 + reg;
            h2f[(s2 * 64 + (row | lf_hi)) * 8 + jj] = (f16)fmaxf(acc[ct][reg] + bbv, 0.f);
        }
    }
    __syncthreads();

    if (wave < 2) {
        floatx4 acc3;
#pragma unroll
        for (int q = 0; q < 4; q++) acc3[q] = 0.f;
#pragma unroll
        for (int step = 0; step < 8; step++) {
            f16x8 af = *(const f16x8*)(&h2f[(step * 64 + lane) * 8]);
            f16x8 bfr = *(const f16x8*)(Wo3f + ((size_t)(step * 2 + wave)) * 512 + lane * 8);
            acc3 = __builtin_amdgcn_mfma_f32_16x16x32_f16(af, bfr, acc3, 0, 0, 0);
        }
        int col = wave * 16 + (lane & 15);
        float pr[4];
#pragma unroll
        for (int reg = 0; reg < 4; reg++) {
            float p = 0.f;
            if (col < 24) {
                int row = lhi * 4 + reg;
                float val = acc3[reg] + bo3[col] + x0[(b * 64 + n0 + row) * 24 + col];
                p = val * Wq2[col];
            }
            pr[reg] = p;
        }
#pragma unroll
        for (int off = 1; off <= 8; off <<= 1)
#pragma unroll
            for (int reg = 0; reg < 4; reg++) pr[reg] += __shfl_xor(pr[reg], off, 64);
        if ((lane & 15) == 0) {
#pragma unroll
            for (int reg = 0; reg < 4; reg++) pq[lhi * 4 + reg][wave] = pr[reg];
        }
    }
    __syncthreads();
    if (tid == 0) {
        float s = ((blk & 3) == 0) ? bq3[0] : 0.f;
#pragma unroll
        for (int r = 0; r < 16; r++)
            s += (pq[r][0] + pq[r][1] + bq2[0]) * Wq3[n0 + r];
        atomicAdd(out + b, s);
    }
}

extern "C" void kernel_launch(void* const* d_in, const int* in_sizes, int n_in,
                              void* d_out, int out_size, void* d_ws, size_t ws_size,
                              hipStream_t stream) {
    const float* data = (const float*)d_in[0];
    const float* act  = (const float*)d_in[1];
    const float* edges = (const float*)d_in[2];
    // d_in[3] rel_rec, d_in[4] rel_send, d_in[5] prediction_steps: structure hardcoded (steps=1)
    const float* Wm1 = (const float*)d_in[6];
    const float* bm1 = (const float*)d_in[7];
    const float* Wm2 = (const float*)d_in[8];
    const float* bm2 = (const float*)d_in[9];
    const float* Wo1 = (const float*)d_in[10];
    const float* bo1 = (const float*)d_in[11];
    const float* Wo2 = (const float*)d_in[12];
    const float* bo2 = (const float*)d_in[13];
    const float* Wo3 = (const float*)d_in[14];
    const float* bo3 = (const float*)d_in[15];
    const float* Wq2 = (const float*)d_in[16];
    const float* bq2 = (const float*)d_in[17];
    const float* Wq3 = (const float*)d_in[18];
    const float* bq3 = (const float*)d_in[19];
    float* out = (float*)d_out;

    char* ws = (char*)d_ws;
    size_t off = 0;
    auto carve = [&](size_t bytes) -> void* {
        void* p = ws + off;
        off += (bytes + 255) & ~(size_t)255;
        return p;
    };
    f16*   u1f  = (f16*)carve((size_t)64 * 2 * 16384 * 2);      // 4 MB, 32x32 A-frag order
    f16*   u2   = (f16*)carve((size_t)64 * 64 * 2 * 256 * 2);   // 4 MB, row order
    float* x0   = (float*)carve((size_t)64 * 64 * 24 * 4);
    float* agg  = (float*)carve((size_t)64 * 64 * 256 * 4);     // 4 MB
    f16*   W2f  = (f16*)carve((size_t)2 * 131072 * 2);          // 512 KB, 32x32 B-frag order
    f16*   Wo1f = (f16*)carve((size_t)9 * 16 * 64 * 8 * 2);
    f16*   Wo2f = (f16*)carve((size_t)8 * 16 * 64 * 8 * 2);
    f16*   Wo3f = (f16*)carve((size_t)8 * 2 * 64 * 8 * 2);

    hipMemsetAsync(d_out, 0, 64 * sizeof(float), stream);
    prep_and_u<<<dim3(290), dim3(256), 0, stream>>>(Wm2, Wo1, Wo2, Wo3, W2f, Wo1f, Wo2f, Wo3f,
                                                    data, act, Wm1, bm1, x0, u1f, u2);
    edge_kernel<<<dim3(1024), dim3(256), 0, stream>>>(u1f, u2, edges, W2f, bm2, agg);
    out_mlp<<<dim3(256), dim3(256), 0, stream>>>(x0, agg, Wo1f, Wo2f, Wo3f, bo1, bo2, bo3,
                                                 Wq2, bq2, Wq3, bq3, out);
}

// Round 7
// 206.638 us; speedup vs baseline: 3.3817x; 3.3817x over previous
//
#include <hip/hip_runtime.h>

typedef _Float16 f16;
typedef __attribute__((ext_vector_type(8))) _Float16 f16x8;
typedef __attribute__((ext_vector_type(4))) float floatx4;
typedef __attribute__((ext_vector_type(16))) float floatx16;

union H8 { f16 h[8]; uint4 v; };

#if defined(__has_builtin)
#if __has_builtin(__builtin_elementwise_max)
#define HAVE_EMAX 1
#endif
#endif

__device__ __forceinline__ f16x8 relu8(f16x8 x) {
    f16x8 z = {};
#ifdef HAVE_EMAX
    return __builtin_elementwise_max(x, z);
#else
    f16x8 r;
#pragma unroll
    for (int j = 0; j < 8; j++) r[j] = x[j] > (f16)0 ? x[j] : (f16)0;
    return r;
#endif
}

// ---------------- P0 (fused): weight prep (fp16 frag tables) + x0/u1/u2 ----------------
// Blocks 0..15: W2f in 32x32x16 B-frag order:
//   W2f[k][step<16][ctg<8][lane<64][j<8] = W2[k][kk=step*16+(lane>>5)*8+j][n=ctg*32+(lane&31)]
// Blocks 16..32: Wo1f/Wo2f in 16x16x32 B-frag order. Block 33: Wo3f.
// Blocks 34..289: compute_u (u1 in 32x32 A-frag order, u2 row order).
__global__ void prep_and_u(const float* __restrict__ Wm2, const float* __restrict__ Wo1,
                           const float* __restrict__ Wo2, const float* __restrict__ Wo3,
                           f16* __restrict__ W2f, f16* __restrict__ Wo1f,
                           f16* __restrict__ Wo2f, f16* __restrict__ Wo3f,
                           const float* __restrict__ data, const float* __restrict__ act,
                           const float* __restrict__ Wm1, const float* __restrict__ bm1,
                           float* __restrict__ x0, f16* __restrict__ u1f, f16* __restrict__ u2) {
    __shared__ float tile[32 * 257];
    __shared__ float t3[256 * 25];
    int id = blockIdx.x;
    int tid = threadIdx.x;
    if (id < 16) {
        // W2 -> 32x32x16 B-frag table
        int k = id >> 3, s = id & 7;               // s = 32-row K chunk
        const float* src = Wm2 + k * 65536;
        int kk0 = s * 32;
        for (int t = tid; t < 32 * 256; t += 256) {
            int r = t >> 8, c = t & 255;
            tile[r * 257 + c] = src[(size_t)(kk0 + r) * 256 + c];
        }
        __syncthreads();
#pragma unroll
        for (int it = 0; it < 4; it++) {
            int t = tid + 256 * it;                // 0..1023 = (ls, ctg, l)
            int ls = t >> 9, ctg = (t >> 6) & 7, l = t & 63;
            int n = ctg * 32 + (l & 31);
            int kkl = ls * 16 + ((l >> 5) & 1) * 8;
            H8 o;
#pragma unroll
            for (int j = 0; j < 8; j++) o.h[j] = (f16)tile[(kkl + j) * 257 + n];
            *(uint4*)(W2f + (size_t)k * 131072 + ((size_t)((s * 2 + ls) * 8 + ctg)) * 512 + l * 8) = o.v;
        }
    } else if (id < 33) {
        const float* src; f16* dst; int s, Ksrc;
        if (id < 25) { s = id - 16; src = Wo1; dst = Wo1f; Ksrc = 280; }
        else         { s = id - 25; src = Wo2; dst = Wo2f; Ksrc = 256; }
        int kk0 = s * 32;
        for (int t = tid; t < 32 * 256; t += 256) {
            int r = t >> 8, c = t & 255;
            tile[r * 257 + c] = (kk0 + r < Ksrc) ? src[(size_t)(kk0 + r) * 256 + c] : 0.f;
        }
        __syncthreads();
#pragma unroll
        for (int it = 0; it < 4; it++) {
            int t = tid + 256 * it;                // (nt, l) for 16x16x32 frags
            int nt = t >> 6, l = t & 63;
            int n = nt * 16 + (l & 15), q = l >> 4;
            H8 o;
#pragma unroll
            for (int j = 0; j < 8; j++) o.h[j] = (f16)tile[(q * 8 + j) * 257 + n];
            *(uint4*)(dst + ((size_t)(s * 16 + nt)) * 512 + l * 8) = o.v;
        }
    } else if (id == 33) {
        for (int t = tid; t < 256 * 24; t += 256) {
            int r = t / 24, c = t - r * 24;
            t3[r * 25 + c] = Wo3[t];
        }
        __syncthreads();
#pragma unroll
        for (int it = 0; it < 4; it++) {
            int e = tid + 256 * it;
            int s3 = e >> 7, nt = (e >> 6) & 1, l = e & 63;
            int n = nt * 16 + (l & 15), q = l >> 4;
            H8 o;
#pragma unroll
            for (int j = 0; j < 8; j++) {
                int kk = s3 * 32 + q * 8 + j;
                o.h[j] = (f16)((n < 24) ? t3[kk * 25 + n] : 0.f);
            }
            *(uint4*)(Wo3f + (size_t)e * 8) = o.v;
        }
    } else {
        // ---- compute_u: u1[b,n,k,h] = x0·W1[k][0:24,h]; u2 = x0·W1[k][24:48,h]+b1 ----
        int r0 = (id - 34) * 16;
        int b = r0 >> 6;
        float* xs = tile;
        for (int idx = tid; idx < 16 * 24; idx += 256) {
            int rr = idx / 24, d = idx - rr * 24;
            int r = r0 + rr;
            float v = (d < 16) ? data[(r * 2) * 16 + d]       // t=0 only (output keeps t=0)
                               : act[(r * 2) * 8 + (d - 16)];
            xs[rr * 24 + d] = v;
            x0[r * 24 + d] = v;
        }
        __syncthreads();
        int h = tid;
        float acc[4][16];
#pragma unroll
        for (int q = 0; q < 4; q++)
#pragma unroll
            for (int rr = 0; rr < 16; rr++) acc[q][rr] = 0.f;
#pragma unroll
        for (int d = 0; d < 24; d++) {
            float w10 = Wm1[(0 * 48 + d) * 256 + h];
            float w11 = Wm1[(1 * 48 + d) * 256 + h];
            float w20 = Wm1[(0 * 48 + 24 + d) * 256 + h];
            float w21 = Wm1[(1 * 48 + 24 + d) * 256 + h];
#pragma unroll
            for (int rr = 0; rr < 16; rr++) {
                float x = xs[rr * 24 + d];
                acc[0][rr] += x * w10;
                acc[1][rr] += x * w11;
                acc[2][rr] += x * w20;
                acc[3][rr] += x * w21;
            }
        }
        float bb0 = bm1[h], bb1 = bm1[256 + h];
        // u1f: 32x32 A-frag order: entry = (step*2+rt)*64 + lane, j
        int step = h >> 4, j = h & 7, lanehalf = (h >> 3) & 1;
#pragma unroll
        for (int rr = 0; rr < 16; rr++) {
            int r = r0 + rr;
            int row = r & 63;
            int entry = (step * 2 + (row >> 5)) * 64 + ((row & 31) | (lanehalf << 5));
            u1f[((size_t)(b * 2 + 0)) * 16384 + entry * 8 + j] = (f16)acc[0][rr];
            u1f[((size_t)(b * 2 + 1)) * 16384 + entry * 8 + j] = (f16)acc[1][rr];
            u2[((size_t)r * 2 + 0) * 256 + h] = (f16)(acc[2][rr] + bb0);
            u2[((size_t)r * 2 + 1) * 256 + h] = (f16)(acc[3][rr] + bb1);
        }
    }
}

// ---------------- K3: edge MLP layer-2 + weighted aggregate ----------------
// block = (b, 4 receivers). u1 frags staged in LDS once per k (shared by 4 i's);
// i-loop is barrier-free. 32x32x16 MFMA, bias folded into acc init.
// launch_bounds(256,3): 64 acc (unified AGPR) + temps must fit ~170 regs — (256,4)
// spilled 585 MB to scratch in R6. Step loop unrolled 4x to cap live B-loads.
__global__ __launch_bounds__(256, 3) void edge_kernel(
    const f16* __restrict__ u1f, const f16* __restrict__ u2, const float* __restrict__ edges,
    const f16* __restrict__ W2f, const float* __restrict__ bm2, float* __restrict__ agg) {
    int blk = blockIdx.x;
    int b = blk >> 4;
    int i0 = (blk & 15) * 4;
    __shared__ __align__(16) f16 u1s[16384];      // 32 KB: [step<16][rt<2][lane<64][8]
    __shared__ __align__(16) f16 u2s[4 * 256];    // 2 KB
    __shared__ float w_s[4 * 64];                 // 1 KB
    __shared__ float aggs[4 * 256];               // 4 KB
    int tid = threadIdx.x;
    int lane = tid & 63, wave = tid >> 6;
    const int l5 = lane >> 5;                     // 0/1: K-half
    const int colBase = wave * 64;

#pragma unroll
    for (int t = tid; t < 1024; t += 256) aggs[t] = 0.f;

#pragma unroll 1
    for (int k = 0; k < 2; k++) {
        __syncthreads();                          // waves done with u1s/u2s of prev k
        {   // stage u1 frags (32 KB, straight copy in frag order)
            const uint4* src = (const uint4*)(u1f + ((size_t)(b * 2 + k)) * 16384);
            uint4* dst = (uint4*)u1s;
#pragma unroll
            for (int it = 0; it < 8; it++) dst[tid + 256 * it] = src[tid + 256 * it];
        }
        if (tid < 128) {                          // stage u2 rows (4 x 256 f16)
            int ii = tid >> 5, u4 = tid & 31;
            *(uint4*)&u2s[ii * 256 + u4 * 8] =
                *(const uint4*)&u2[((size_t)(b * 64 + i0 + ii) * 2 + k) * 256 + u4 * 8];
        }
        {   // stage edge weights (4 x 64)
            int ii = tid >> 6, j = tid & 63;
            int ia = i0 + ii;
            float w = 0.f;
            if (j != ia) {
                int jj = j - (j > ia ? 1 : 0);
                w = edges[((size_t)b * 4032 + (size_t)ia * 63 + jj) * 2 + k];
            }
            w_s[tid] = w;
        }
        float bb[2];
#pragma unroll
        for (int ct = 0; ct < 2; ct++) bb[ct] = bm2[k * 256 + colBase + ct * 32 + (lane & 31)];
        __syncthreads();

        const f16* Wkb = W2f + (size_t)k * 131072 + (size_t)(wave * 2) * 512 + lane * 8;

#pragma unroll 1
        for (int il = 0; il < 4; il++) {
            floatx16 acc[2][2];                   // [rt][ct], bias pre-folded
#pragma unroll
            for (int rt = 0; rt < 2; rt++)
#pragma unroll
                for (int ct = 0; ct < 2; ct++)
#pragma unroll
                    for (int q = 0; q < 16; q++) acc[rt][ct][q] = bb[ct];

            const f16* pu2 = &u2s[il * 256 + l5 * 8];
#pragma unroll 4
            for (int step = 0; step < 16; step++) {
                f16x8 bfr[2];
#pragma unroll
                for (int ct = 0; ct < 2; ct++)
                    bfr[ct] = *(const f16x8*)(Wkb + (size_t)(step * 8 + ct) * 512);
                f16x8 uv = *(const f16x8*)(pu2 + step * 16);
                f16x8 af[2];
#pragma unroll
                for (int rt = 0; rt < 2; rt++) {
                    f16x8 u1v = *(const f16x8*)&u1s[((step * 2 + rt) * 64 + lane) * 8];
                    af[rt] = relu8(u1v + uv);
                }
#pragma unroll
                for (int rt = 0; rt < 2; rt++)
#pragma unroll
                    for (int ct = 0; ct < 2; ct++)
                        acc[rt][ct] = __builtin_amdgcn_mfma_f32_32x32x16_f16(
                            af[rt], bfr[ct], acc[rt][ct], 0, 0, 0);
            }
            // epilogue: sum_j relu(C)*w.  C: col=lane&31, row=(reg&3)+8*(reg>>2)+4*(lane>>5)
#pragma unroll
            for (int ct = 0; ct < 2; ct++) {
                float p = 0.f;
#pragma unroll
                for (int rt = 0; rt < 2; rt++) {
                    const float* wr = &w_s[il * 64 + rt * 32 + l5 * 4];
#pragma unroll
                    for (int g = 0; g < 4; g++) {
                        float4 wv = *(const float4*)(wr + g * 8);
                        p += fmaxf(acc[rt][ct][g * 4 + 0], 0.f) * wv.x;
                        p += fmaxf(acc[rt][ct][g * 4 + 1], 0.f) * wv.y;
                        p += fmaxf(acc[rt][ct][g * 4 + 2], 0.f) * wv.z;
                        p += fmaxf(acc[rt][ct][g * 4 + 3], 0.f) * wv.w;
                    }
                }
                p += __shfl_xor(p, 32, 64);
                if (l5 == 0) aggs[il * 256 + colBase + ct * 32 + lane] += p;  // wave-private cols
            }
        }
    }
    __syncthreads();
#pragma unroll
    for (int t = tid; t < 1024; t += 256)
        agg[((size_t)(b * 64 + i0 + (t >> 8))) * 256 + (t & 255)] = aggs[t];
}

// ---------------- K4: out-MLP, 4 blocks per batch (M=16 rows each) ----------------
__global__ void out_mlp(const float* __restrict__ x0, const float* __restrict__ agg,
                        const f16* __restrict__ Wo1f, const f16* __restrict__ Wo2f,
                        const f16* __restrict__ Wo3f,
                        const float* __restrict__ bo1, const float* __restrict__ bo2,
                        const float* __restrict__ bo3,
                        const float* __restrict__ Wq2, const float* __restrict__ bq2,
                        const float* __restrict__ Wq3, const float* __restrict__ bq3,
                        float* __restrict__ out) {
    int blk = blockIdx.x;
    int b = blk >> 2, n0 = (blk & 3) * 16;
    int tid = threadIdx.x;
    int lane = tid & 63, wave = tid >> 6;
    const int colBase = wave * 64;
    const int lhi = lane >> 4;
    __shared__ __align__(16) f16 A1f[9 * 64 * 8];
    __shared__ __align__(16) f16 A2f[8 * 64 * 8];
    __shared__ __align__(16) f16 h2f[8 * 64 * 8];
    __shared__ float pq[16][2];

    for (int t = tid; t < 576; t += 256) {
        int lane_f = t & 63, s = t >> 6;
        int m = n0 + (lane_f & 15);
        int c0 = s * 32 + (lane_f >> 4) * 8;
        float vals[8];
        if (c0 < 24) {
            const float4* xr = (const float4*)(x0 + (b * 64 + m) * 24 + c0);
            float4 a = xr[0], c = xr[1];
            vals[0] = a.x; vals[1] = a.y; vals[2] = a.z; vals[3] = a.w;
            vals[4] = c.x; vals[5] = c.y; vals[6] = c.z; vals[7] = c.w;
        } else if (c0 < 280) {
            const float4* ar = (const float4*)(agg + ((size_t)(b * 64 + m)) * 256 + (c0 - 24));
            float4 a = ar[0], c = ar[1];
            vals[0] = a.x; vals[1] = a.y; vals[2] = a.z; vals[3] = a.w;
            vals[4] = c.x; vals[5] = c.y; vals[6] = c.z; vals[7] = c.w;
        } else {
#pragma unroll
            for (int q = 0; q < 8; q++) vals[q] = 0.f;
        }
        H8 o;
#pragma unroll
        for (int q = 0; q < 8; q++) o.h[q] = (f16)vals[q];
        *(uint4*)(&A1f[t * 8]) = o.v;
    }
    __syncthreads();

    floatx4 acc[4];
#pragma unroll
    for (int ct = 0; ct < 4; ct++)
#pragma unroll
        for (int q = 0; q < 4; q++) acc[ct][q] = 0.f;
#pragma unroll
    for (int step = 0; step < 9; step++) {
        f16x8 af = *(const f16x8*)(&A1f[(step * 64 + lane) * 8]);
#pragma unroll
        for (int ct = 0; ct < 4; ct++) {
            f16x8 bfr = *(const f16x8*)(Wo1f + ((size_t)(step * 16 + wave * 4 + ct)) * 512 + lane * 8);
            acc[ct] = __builtin_amdgcn_mfma_f32_16x16x32_f16(af, bfr, acc[ct], 0, 0, 0);
        }
    }
#pragma unroll
    for (int ct = 0; ct < 4; ct++) {
        int col = colBase + ct * 16 + (lane & 15);
        float bbv = bo1[col];
        int s2 = col >> 5, jj = col & 7, lf_hi = ((col >> 3) & 3) << 4;
#pragma unroll
        for (int reg = 0; reg < 4; reg++) {
            int row = lhi * 4 + reg;
            A2f[(s2 * 64 + (row | lf_hi)) * 8 + jj] = (f16)fmaxf(acc[ct][reg] + bbv, 0.f);
        }
    }
    __syncthreads();

#pragma unroll
    for (int ct = 0; ct < 4; ct++)
#pragma unroll
        for (int q = 0; q < 4; q++) acc[ct][q] = 0.f;
#pragma unroll
    for (int step = 0; step < 8; step++) {
        f16x8 af = *(const f16x8*)(&A2f[(step * 64 + lane) * 8]);
#pragma unroll
        for (int ct = 0; ct < 4; ct++) {
            f16x8 bfr = *(const f16x8*)(Wo2f + ((size_t)(step * 16 + wave * 4 + ct)) * 512 + lane * 8);
            acc[ct] = __builtin_amdgcn_mfma_f32_16x16x32_f16(af, bfr, acc[ct], 0, 0, 0);
        }
    }
#pragma unroll
    for (int ct = 0; ct < 4; ct++) {
        int col = colBase + ct * 16 + (lane & 15);
        float bbv = bo2[col];
        int s2 = col >> 5, jj = col & 7, lf_hi = ((col >> 3) & 3) << 4;
#pragma unroll
        for (int reg = 0; reg < 4; reg++) {
            int row = lhi * 4 + reg;
            h2f[(s2 * 64 + (row | lf_hi)) * 8 + jj] = (f16)fmaxf(acc[ct][reg] + bbv, 0.f);
        }
    }
    __syncthreads();

    if (wave < 2) {
        floatx4 acc3;
#pragma unroll
        for (int q = 0; q < 4; q++) acc3[q] = 0.f;
#pragma unroll
        for (int step = 0; step < 8; step++) {
            f16x8 af = *(const f16x8*)(&h2f[(step * 64 + lane) * 8]);
            f16x8 bfr = *(const f16x8*)(Wo3f + ((size_t)(step * 2 + wave)) * 512 + lane * 8);
            acc3 = __builtin_amdgcn_mfma_f32_16x16x32_f16(af, bfr, acc3, 0, 0, 0);
        }
        int col = wave * 16 + (lane & 15);
        float pr[4];
#pragma unroll
        for (int reg = 0; reg < 4; reg++) {
            float p = 0.f;
            if (col < 24) {
                int row = lhi * 4 + reg;
                float val = acc3[reg] + bo3[col] + x0[(b * 64 + n0 + row) * 24 + col];
                p = val * Wq2[col];
            }
            pr[reg] = p;
        }
#pragma unroll
        for (int off = 1; off <= 8; off <<= 1)
#pragma unroll
            for (int reg = 0; reg < 4; reg++) pr[reg] += __shfl_xor(pr[reg], off, 64);
        if ((lane & 15) == 0) {
#pragma unroll
            for (int reg = 0; reg < 4; reg++) pq[lhi * 4 + reg][wave] = pr[reg];
        }
    }
    __syncthreads();
    if (tid == 0) {
        float s = ((blk & 3) == 0) ? bq3[0] : 0.f;
#pragma unroll
        for (int r = 0; r < 16; r++)
            s += (pq[r][0] + pq[r][1] + bq2[0]) * Wq3[n0 + r];
        atomicAdd(out + b, s);
    }
}

extern "C" void kernel_launch(void* const* d_in, const int* in_sizes, int n_in,
                              void* d_out, int out_size, void* d_ws, size_t ws_size,
                              hipStream_t stream) {
    const float* data = (const float*)d_in[0];
    const float* act  = (const float*)d_in[1];
    const float* edges = (const float*)d_in[2];
    // d_in[3] rel_rec, d_in[4] rel_send, d_in[5] prediction_steps: structure hardcoded (steps=1)
    const float* Wm1 = (const float*)d_in[6];
    const float* bm1 = (const float*)d_in[7];
    const float* Wm2 = (const float*)d_in[8];
    const float* bm2 = (const float*)d_in[9];
    const float* Wo1 = (const float*)d_in[10];
    const float* bo1 = (const float*)d_in[11];
    const float* Wo2 = (const float*)d_in[12];
    const float* bo2 = (const float*)d_in[13];
    const float* Wo3 = (const float*)d_in[14];
    const float* bo3 = (const float*)d_in[15];
    const float* Wq2 = (const float*)d_in[16];
    const float* bq2 = (const float*)d_in[17];
    const float* Wq3 = (const float*)d_in[18];
    const float* bq3 = (const float*)d_in[19];
    float* out = (float*)d_out;

    char* ws = (char*)d_ws;
    size_t off = 0;
    auto carve = [&](size_t bytes) -> void* {
        void* p = ws + off;
        off += (bytes + 255) & ~(size_t)255;
        return p;
    };
    f16*   u1f  = (f16*)carve((size_t)64 * 2 * 16384 * 2);      // 4 MB, 32x32 A-frag order
    f16*   u2   = (f16*)carve((size_t)64 * 64 * 2 * 256 * 2);   // 4 MB, row order
    float* x0   = (float*)carve((size_t)64 * 64 * 24 * 4);
    float* agg  = (float*)carve((size_t)64 * 64 * 256 * 4);     // 4 MB
    f16*   W2f  = (f16*)carve((size_t)2 * 131072 * 2);          // 512 KB, 32x32 B-frag order
    f16*   Wo1f = (f16*)carve((size_t)9 * 16 * 64 * 8 * 2);
    f16*   Wo2f = (f16*)carve((size_t)8 * 16 * 64 * 8 * 2);
    f16*   Wo3f = (f16*)carve((size_t)8 * 2 * 64 * 8 * 2);

    hipMemsetAsync(d_out, 0, 64 * sizeof(float), stream);
    prep_and_u<<<dim3(290), dim3(256), 0, stream>>>(Wm2, Wo1, Wo2, Wo3, W2f, Wo1f, Wo2f, Wo3f,
                                                    data, act, Wm1, bm1, x0, u1f, u2);
    edge_kernel<<<dim3(1024), dim3(256), 0, stream>>>(u1f, u2, edges, W2f, bm2, agg);
    out_mlp<<<dim3(256), dim3(256), 0, stream>>>(x0, agg, Wo1f, Wo2f, Wo3f, bo1, bo2, bo3,
                                                 Wq2, bq2, Wq3, bq3, out);
}

// Round 8
// 203.265 us; speedup vs baseline: 3.4378x; 1.0166x over previous
//
#include <hip/hip_runtime.h>

typedef _Float16 f16;
typedef __attribute__((ext_vector_type(8))) _Float16 f16x8;
typedef __attribute__((ext_vector_type(4))) float floatx4;
typedef __attribute__((ext_vector_type(16))) float floatx16;

union H8 { f16 h[8]; uint4 v; };

#if defined(__has_builtin)
#if __has_builtin(__builtin_elementwise_max)
#define HAVE_EMAX 1
#endif
#endif

__device__ __forceinline__ f16x8 relu8(f16x8 x) {
    f16x8 z = {};
#ifdef HAVE_EMAX
    return __builtin_elementwise_max(x, z);
#else
    f16x8 r;
#pragma unroll
    for (int j = 0; j < 8; j++) r[j] = x[j] > (f16)0 ? x[j] : (f16)0;
    return r;
#endif
}

// ---------------- P0 (fused): weight prep (fp16 frag tables) + x0/u1/u2 + out zero ----------------
// Blocks 0..15: W2f in 32x32x16 B-frag order:
//   W2f[k][step<16][ctg<8][lane<64][j<8] = W2[k][kk=step*16+(lane>>5)*8+j][n=ctg*32+(lane&31)]
// Blocks 16..32: Wo1f/Wo2f in 16x16x32 B-frag order. Block 33: Wo3f.
// Blocks 34..289: compute_u (u1 in 32x32 A-frag order, u2 row order). Block 290: zero out.
__global__ void prep_and_u(const float* __restrict__ Wm2, const float* __restrict__ Wo1,
                           const float* __restrict__ Wo2, const float* __restrict__ Wo3,
                           f16* __restrict__ W2f, f16* __restrict__ Wo1f,
                           f16* __restrict__ Wo2f, f16* __restrict__ Wo3f,
                           const float* __restrict__ data, const float* __restrict__ act,
                           const float* __restrict__ Wm1, const float* __restrict__ bm1,
                           float* __restrict__ x0, f16* __restrict__ u1f, f16* __restrict__ u2,
                           float* __restrict__ out) {
    __shared__ float tile[32 * 257];
    __shared__ float t3[256 * 25];
    int id = blockIdx.x;
    int tid = threadIdx.x;
    if (id < 16) {
        // W2 -> 32x32x16 B-frag table
        int k = id >> 3, s = id & 7;               // s = 32-row K chunk
        const float* src = Wm2 + k * 65536;
        int kk0 = s * 32;
        for (int t = tid; t < 32 * 256; t += 256) {
            int r = t >> 8, c = t & 255;
            tile[r * 257 + c] = src[(size_t)(kk0 + r) * 256 + c];
        }
        __syncthreads();
#pragma unroll
        for (int it = 0; it < 4; it++) {
            int t = tid + 256 * it;                // 0..1023 = (ls, ctg, l)
            int ls = t >> 9, ctg = (t >> 6) & 7, l = t & 63;
            int n = ctg * 32 + (l & 31);
            int kkl = ls * 16 + ((l >> 5) & 1) * 8;
            H8 o;
#pragma unroll
            for (int j = 0; j < 8; j++) o.h[j] = (f16)tile[(kkl + j) * 257 + n];
            *(uint4*)(W2f + (size_t)k * 131072 + ((size_t)((s * 2 + ls) * 8 + ctg)) * 512 + l * 8) = o.v;
        }
    } else if (id < 33) {
        const float* src; f16* dst; int s, Ksrc;
        if (id < 25) { s = id - 16; src = Wo1; dst = Wo1f; Ksrc = 280; }
        else         { s = id - 25; src = Wo2; dst = Wo2f; Ksrc = 256; }
        int kk0 = s * 32;
        for (int t = tid; t < 32 * 256; t += 256) {
            int r = t >> 8, c = t & 255;
            tile[r * 257 + c] = (kk0 + r < Ksrc) ? src[(size_t)(kk0 + r) * 256 + c] : 0.f;
        }
        __syncthreads();
#pragma unroll
        for (int it = 0; it < 4; it++) {
            int t = tid + 256 * it;                // (nt, l) for 16x16x32 frags
            int nt = t >> 6, l = t & 63;
            int n = nt * 16 + (l & 15), q = l >> 4;
            H8 o;
#pragma unroll
            for (int j = 0; j < 8; j++) o.h[j] = (f16)tile[(q * 8 + j) * 257 + n];
            *(uint4*)(dst + ((size_t)(s * 16 + nt)) * 512 + l * 8) = o.v;
        }
    } else if (id == 33) {
        for (int t = tid; t < 256 * 24; t += 256) {
            int r = t / 24, c = t - r * 24;
            t3[r * 25 + c] = Wo3[t];
        }
        __syncthreads();
#pragma unroll
        for (int it = 0; it < 4; it++) {
            int e = tid + 256 * it;
            int s3 = e >> 7, nt = (e >> 6) & 1, l = e & 63;
            int n = nt * 16 + (l & 15), q = l >> 4;
            H8 o;
#pragma unroll
            for (int j = 0; j < 8; j++) {
                int kk = s3 * 32 + q * 8 + j;
                o.h[j] = (f16)((n < 24) ? t3[kk * 25 + n] : 0.f);
            }
            *(uint4*)(Wo3f + (size_t)e * 8) = o.v;
        }
    } else if (id == 290) {
        if (tid < 64) out[tid] = 0.f;              // out_mlp accumulates via atomicAdd
    } else {
        // ---- compute_u: u1[b,n,k,h] = x0·W1[k][0:24,h]; u2 = x0·W1[k][24:48,h]+b1 ----
        int r0 = (id - 34) * 16;
        int b = r0 >> 6;
        float* xs = tile;
        for (int idx = tid; idx < 16 * 24; idx += 256) {
            int rr = idx / 24, d = idx - rr * 24;
            int r = r0 + rr;
            float v = (d < 16) ? data[(r * 2) * 16 + d]       // t=0 only (output keeps t=0)
                               : act[(r * 2) * 8 + (d - 16)];
            xs[rr * 24 + d] = v;
            x0[r * 24 + d] = v;
        }
        __syncthreads();
        int h = tid;
        float acc[4][16];
#pragma unroll
        for (int q = 0; q < 4; q++)
#pragma unroll
            for (int rr = 0; rr < 16; rr++) acc[q][rr] = 0.f;
#pragma unroll
        for (int d = 0; d < 24; d++) {
            float w10 = Wm1[(0 * 48 + d) * 256 + h];
            float w11 = Wm1[(1 * 48 + d) * 256 + h];
            float w20 = Wm1[(0 * 48 + 24 + d) * 256 + h];
            float w21 = Wm1[(1 * 48 + 24 + d) * 256 + h];
#pragma unroll
            for (int rr = 0; rr < 16; rr++) {
                float x = xs[rr * 24 + d];
                acc[0][rr] += x * w10;
                acc[1][rr] += x * w11;
                acc[2][rr] += x * w20;
                acc[3][rr] += x * w21;
            }
        }
        float bb0 = bm1[h], bb1 = bm1[256 + h];
        // u1f: 32x32 A-frag order: entry = (step*2+rt)*64 + lane, j
        int step = h >> 4, j = h & 7, lanehalf = (h >> 3) & 1;
#pragma unroll
        for (int rr = 0; rr < 16; rr++) {
            int r = r0 + rr;
            int row = r & 63;
            int entry = (step * 2 + (row >> 5)) * 64 + ((row & 31) | (lanehalf << 5));
            u1f[((size_t)(b * 2 + 0)) * 16384 + entry * 8 + j] = (f16)acc[0][rr];
            u1f[((size_t)(b * 2 + 1)) * 16384 + entry * 8 + j] = (f16)acc[1][rr];
            u2[((size_t)r * 2 + 0) * 256 + h] = (f16)(acc[2][rr] + bb0);
            u2[((size_t)r * 2 + 1) * 256 + h] = (f16)(acc[3][rr] + bb1);
        }
    }
}

// ---------------- K3: edge MLP layer-2 + weighted aggregate ----------------
// block = (b, 4 receivers). Per (k,il): A = relu(u1+u2[il]) built COOPERATIVELY
// (once per block, not per wave — R7 rebuilt it 4x redundantly) into Af LDS in
// 32x32 A-frag order; MFMA phase is pure {global bfr, ds_read af, mfma}.
// (256,3): 64 unified acc regs + temps must stay under ~170 (R6 spilled at (256,4)).
__global__ __launch_bounds__(256, 3) void edge_kernel(
    const f16* __restrict__ u1f, const f16* __restrict__ u2, const float* __restrict__ edges,
    const f16* __restrict__ W2f, const float* __restrict__ bm2, float* __restrict__ agg) {
    int blk = blockIdx.x;
    int b = blk >> 4;
    int i0 = (blk & 15) * 4;
    __shared__ __align__(16) f16 Af[16384];       // 32 KB: [step<16][rt<2][lane<64][8]
    __shared__ __align__(16) f16 u2s[4 * 256];    // 2 KB
    __shared__ float w_s[4 * 64];                 // 1 KB
    __shared__ float aggs[4 * 256];               // 4 KB   (39.9 KB total)
    int tid = threadIdx.x;
    int lane = tid & 63, wave = tid >> 6;
    const int l5 = lane >> 5;                     // 0/1: K-half
    const int colBase = wave * 64;

#pragma unroll
    for (int t = tid; t < 1024; t += 256) aggs[t] = 0.f;

#pragma unroll 1
    for (int k = 0; k < 2; k++) {
        __syncthreads();                          // prev-k MFMA readers done with u2s
        if (tid < 128) {                          // stage u2 rows (4 x 256 f16)
            int ii = tid >> 5, u4 = tid & 31;
            *(uint4*)&u2s[ii * 256 + u4 * 8] =
                *(const uint4*)&u2[((size_t)(b * 64 + i0 + ii) * 2 + k) * 256 + u4 * 8];
        }
        {   // stage edge weights (4 x 64)
            int ii = tid >> 6, j = tid & 63;
            int ia = i0 + ii;
            float w = 0.f;
            if (j != ia) {
                int jj = j - (j > ia ? 1 : 0);
                w = edges[((size_t)b * 4032 + (size_t)ia * 63 + jj) * 2 + k];
            }
            w_s[tid] = w;
        }
        float bb[2];
#pragma unroll
        for (int ct = 0; ct < 2; ct++) bb[ct] = bm2[k * 256 + colBase + ct * 32 + (lane & 31)];
        const f16* u1base = u1f + ((size_t)(b * 2 + k)) * 16384;
        const f16* Wkb = W2f + (size_t)k * 131072 + (size_t)(wave * 2) * 512 + lane * 8;

#pragma unroll 1
        for (int il = 0; il < 4; il++) {
            __syncthreads();                      // u2s/w_s ready; prev-il MFMA done with Af
            // cooperative build: 2048 b128 entries, 8 per thread, frag order
#pragma unroll
            for (int it = 0; it < 8; it++) {
                int e = tid + 256 * it;           // entry = (step*2+rt)*64 + lane_f
                f16x8 a = *(const f16x8*)(u1base + (size_t)e * 8);
                int c8 = ((e >> 7) << 4) + ((e >> 5) & 1) * 8;   // step*16 + half*8
                f16x8 uv = *(const f16x8*)&u2s[il * 256 + c8];   // broadcast within 32
                *(f16x8*)&Af[e * 8] = relu8(a + uv);
            }
            __syncthreads();

            floatx16 acc[2][2];                   // [rt][ct], bias pre-folded
#pragma unroll
            for (int rt = 0; rt < 2; rt++)
#pragma unroll
                for (int ct = 0; ct < 2; ct++)
#pragma unroll
                    for (int q = 0; q < 16; q++) acc[rt][ct][q] = bb[ct];

#pragma unroll 4
            for (int step = 0; step < 16; step++) {
                f16x8 bfr[2];
#pragma unroll
                for (int ct = 0; ct < 2; ct++)
                    bfr[ct] = *(const f16x8*)(Wkb + (size_t)(step * 8 + ct) * 512);
                f16x8 af[2];
#pragma unroll
                for (int rt = 0; rt < 2; rt++)
                    af[rt] = *(const f16x8*)&Af[((step * 2 + rt) * 64 + lane) * 8];
#pragma unroll
                for (int rt = 0; rt < 2; rt++)
#pragma unroll
                    for (int ct = 0; ct < 2; ct++)
                        acc[rt][ct] = __builtin_amdgcn_mfma_f32_32x32x16_f16(
                            af[rt], bfr[ct], acc[rt][ct], 0, 0, 0);
            }
            // epilogue: sum_j relu(C)*w.  C: col=lane&31, row=(reg&3)+8*(reg>>2)+4*(lane>>5)
#pragma unroll
            for (int ct = 0; ct < 2; ct++) {
                float p = 0.f;
#pragma unroll
                for (int rt = 0; rt < 2; rt++) {
                    const float* wr = &w_s[il * 64 + rt * 32 + l5 * 4];
#pragma unroll
                    for (int g = 0; g < 4; g++) {
                        float4 wv = *(const float4*)(wr + g * 8);
                        p += fmaxf(acc[rt][ct][g * 4 + 0], 0.f) * wv.x;
                        p += fmaxf(acc[rt][ct][g * 4 + 1], 0.f) * wv.y;
                        p += fmaxf(acc[rt][ct][g * 4 + 2], 0.f) * wv.z;
                        p += fmaxf(acc[rt][ct][g * 4 + 3], 0.f) * wv.w;
                    }
                }
                p += __shfl_xor(p, 32, 64);
                if (l5 == 0) aggs[il * 256 + colBase + ct * 32 + lane] += p;  // wave-private cols
            }
        }
    }
    __syncthreads();
#pragma unroll
    for (int t = tid; t < 1024; t += 256)
        agg[((size_t)(b * 64 + i0 + (t >> 8))) * 256 + (t & 255)] = aggs[t];
}

// ---------------- K4: out-MLP, 4 blocks per batch (M=16 rows each) ----------------
__global__ void out_mlp(const float* __restrict__ x0, const float* __restrict__ agg,
                        const f16* __restrict__ Wo1f, const f16* __restrict__ Wo2f,
                        const f16* __restrict__ Wo3f,
                        const float* __restrict__ bo1, const float* __restrict__ bo2,
                        const float* __restrict__ bo3,
                        const float* __restrict__ Wq2, const float* __restrict__ bq2,
                        const float* __restrict__ Wq3, const float* __restrict__ bq3,
                        float* __restrict__ out) {
    int blk = blockIdx.x;
    int b = blk >> 2, n0 = (blk & 3) * 16;
    int tid = threadIdx.x;
    int lane = tid & 63, wave = tid >> 6;
    const int colBase = wave * 64;
    const int lhi = lane >> 4;
    __shared__ __align__(16) f16 A1f[9 * 64 * 8];
    __shared__ __align__(16) f16 A2f[8 * 64 * 8];
    __shared__ __align__(16) f16 h2f[8 * 64 * 8];
    __shared__ float pq[16][2];

    for (int t = tid; t < 576; t += 256) {
        int lane_f = t & 63, s = t >> 6;
        int m = n0 + (lane_f & 15);
        int c0 = s * 32 + (lane_f >> 4) * 8;
        float vals[8];
        if (c0 < 24) {
            const float4* xr = (const float4*)(x0 + (b * 64 + m) * 24 + c0);
            float4 a = xr[0], c = xr[1];
            vals[0] = a.x; vals[1] = a.y; vals[2] = a.z; vals[3] = a.w;
            vals[4] = c.x; vals[5] = c.y; vals[6] = c.z; vals[7] = c.w;
        } else if (c0 < 280) {
            const float4* ar = (const float4*)(agg + ((size_t)(b * 64 + m)) * 256 + (c0 - 24));
            float4 a = ar[0], c = ar[1];
            vals[0] = a.x; vals[1] = a.y; vals[2] = a.z; vals[3] = a.w;
            vals[4] = c.x; vals[5] = c.y; vals[6] = c.z; vals[7] = c.w;
        } else {
#pragma unroll
            for (int q = 0; q < 8; q++) vals[q] = 0.f;
        }
        H8 o;
#pragma unroll
        for (int q = 0; q < 8; q++) o.h[q] = (f16)vals[q];
        *(uint4*)(&A1f[t * 8]) = o.v;
    }
    __syncthreads();

    floatx4 acc[4];
#pragma unroll
    for (int ct = 0; ct < 4; ct++)
#pragma unroll
        for (int q = 0; q < 4; q++) acc[ct][q] = 0.f;
#pragma unroll
    for (int step = 0; step < 9; step++) {
        f16x8 af = *(const f16x8*)(&A1f[(step * 64 + lane) * 8]);
#pragma unroll
        for (int ct = 0; ct < 4; ct++) {
            f16x8 bfr = *(const f16x8*)(Wo1f + ((size_t)(step * 16 + wave * 4 + ct)) * 512 + lane * 8);
            acc[ct] = __builtin_amdgcn_mfma_f32_16x16x32_f16(af, bfr, acc[ct], 0, 0, 0);
        }
    }
#pragma unroll
    for (int ct = 0; ct < 4; ct++) {
        int col = colBase + ct * 16 + (lane & 15);
        float bbv = bo1[col];
        int s2 = col >> 5, jj = col & 7, lf_hi = ((col >> 3) & 3) << 4;
#pragma unroll
        for (int reg = 0; reg < 4; reg++) {
            int row = lhi * 4 + reg;
            A2f[(s2 * 64 + (row | lf_hi)) * 8 + jj] = (f16)fmaxf(acc[ct][reg] + bbv, 0.f);
        }
    }
    __syncthreads();

#pragma unroll
    for (int ct = 0; ct < 4; ct++)
#pragma unroll
        for (int q = 0; q < 4; q++) acc[ct][q] = 0.f;
#pragma unroll
    for (int step = 0; step < 8; step++) {
        f16x8 af = *(const f16x8*)(&A2f[(step * 64 + lane) * 8]);
#pragma unroll
        for (int ct = 0; ct < 4; ct++) {
            f16x8 bfr = *(const f16x8*)(Wo2f + ((size_t)(step * 16 + wave * 4 + ct)) * 512 + lane * 8);
            acc[ct] = __builtin_amdgcn_mfma_f32_16x16x32_f16(af, bfr, acc[ct], 0, 0, 0);
        }
    }
#pragma unroll
    for (int ct = 0; ct < 4; ct++) {
        int col = colBase + ct * 16 + (lane & 15);
        float bbv = bo2[col];
        int s2 = col >> 5, jj = col & 7, lf_hi = ((col >> 3) & 3) << 4;
#pragma unroll
        for (int reg = 0; reg < 4; reg++) {
            int row = lhi * 4 + reg;
            h2f[(s2 * 64 + (row | lf_hi)) * 8 + jj] = (f16)fmaxf(acc[ct][reg] + bbv, 0.f);
        }
    }
    __syncthreads();

    if (wave < 2) {
        floatx4 acc3;
#pragma unroll
        for (int q = 0; q < 4; q++) acc3[q] = 0.f;
#pragma unroll
        for (int step = 0; step < 8; step++) {
            f16x8 af = *(const f16x8*)(&h2f[(step * 64 + lane) * 8]);
            f16x8 bfr = *(const f16x8*)(Wo3f + ((size_t)(step * 2 + wave)) * 512 + lane * 8);
            acc3 = __builtin_amdgcn_mfma_f32_16x16x32_f16(af, bfr, acc3, 0, 0, 0);
        }
        int col = wave * 16 + (lane & 15);
        float pr[4];
#pragma unroll
        for (int reg = 0; reg < 4; reg++) {
            float p = 0.f;
            if (col < 24) {
                int row = lhi * 4 + reg;
                float val = acc3[reg] + bo3[col] + x0[(b * 64 + n0 + row) * 24 + col];
                p = val * Wq2[col];
            }
            pr[reg] = p;
        }
#pragma unroll
        for (int off = 1; off <= 8; off <<= 1)
#pragma unroll
            for (int reg = 0; reg < 4; reg++) pr[reg] += __shfl_xor(pr[reg], off, 64);
        if ((lane & 15) == 0) {
#pragma unroll
            for (int reg = 0; reg < 4; reg++) pq[lhi * 4 + reg][wave] = pr[reg];
        }
    }
    __syncthreads();
    if (tid == 0) {
        float s = ((blk & 3) == 0) ? bq3[0] : 0.f;
#pragma unroll
        for (int r = 0; r < 16; r++)
            s += (pq[r][0] + pq[r][1] + bq2[0]) * Wq3[n0 + r];
        atomicAdd(out + b, s);
    }
}

extern "C" void kernel_launch(void* const* d_in, const int* in_sizes, int n_in,
                              void* d_out, int out_size, void* d_ws, size_t ws_size,
                              hipStream_t stream) {
    const float* data = (const float*)d_in[0];
    const float* act  = (const float*)d_in[1];
    const float* edges = (const float*)d_in[2];
    // d_in[3] rel_rec, d_in[4] rel_send, d_in[5] prediction_steps: structure hardcoded (steps=1)
    const float* Wm1 = (const float*)d_in[6];
    const float* bm1 = (const float*)d_in[7];
    const float* Wm2 = (const float*)d_in[8];
    const float* bm2 = (const float*)d_in[9];
    const float* Wo1 = (const float*)d_in[10];
    const float* bo1 = (const float*)d_in[11];
    const float* Wo2 = (const float*)d_in[12];
    const float* bo2 = (const float*)d_in[13];
    const float* Wo3 = (const float*)d_in[14];
    const float* bo3 = (const float*)d_in[15];
    const float* Wq2 = (const float*)d_in[16];
    const float* bq2 = (const float*)d_in[17];
    const float* Wq3 = (const float*)d_in[18];
    const float* bq3 = (const float*)d_in[19];
    float* out = (float*)d_out;

    char* ws = (char*)d_ws;
    size_t off = 0;
    auto carve = [&](size_t bytes) -> void* {
        void* p = ws + off;
        off += (bytes + 255) & ~(size_t)255;
        return p;
    };
    f16*   u1f  = (f16*)carve((size_t)64 * 2 * 16384 * 2);      // 4 MB, 32x32 A-frag order
    f16*   u2   = (f16*)carve((size_t)64 * 64 * 2 * 256 * 2);   // 4 MB, row order
    float* x0   = (float*)carve((size_t)64 * 64 * 24 * 4);
    float* agg  = (float*)carve((size_t)64 * 64 * 256 * 4);     // 4 MB
    f16*   W2f  = (f16*)carve((size_t)2 * 131072 * 2);          // 512 KB, 32x32 B-frag order
    f16*   Wo1f = (f16*)carve((size_t)9 * 16 * 64 * 8 * 2);
    f16*   Wo2f = (f16*)carve((size_t)8 * 16 * 64 * 8 * 2);
    f16*   Wo3f = (f16*)carve((size_t)8 * 2 * 64 * 8 * 2);

    prep_and_u<<<dim3(291), dim3(256), 0, stream>>>(Wm2, Wo1, Wo2, Wo3, W2f, Wo1f, Wo2f, Wo3f,
                                                    data, act, Wm1, bm1, x0, u1f, u2, out);
    edge_kernel<<<dim3(1024), dim3(256), 0, stream>>>(u1f, u2, edges, W2f, bm2, agg);
    out_mlp<<<dim3(256), dim3(256), 0, stream>>>(x0, agg, Wo1f, Wo2f, Wo3f, bo1, bo2, bo3,
                                                 Wq2, bq2, Wq3, bq3, out);
}

// Round 9
// 199.312 us; speedup vs baseline: 3.5060x; 1.0198x over previous
//
#include <hip/hip_runtime.h>

typedef _Float16 f16;
typedef __attribute__((ext_vector_type(8))) _Float16 f16x8;
typedef __attribute__((ext_vector_type(4))) float floatx4;
typedef __attribute__((ext_vector_type(16))) float floatx16;

union H8 { f16 h[8]; uint4 v; };

#if defined(__has_builtin)
#if __has_builtin(__builtin_elementwise_max)
#define HAVE_EMAX 1
#endif
#endif

__device__ __forceinline__ f16x8 relu8(f16x8 x) {
    f16x8 z = {};
#ifdef HAVE_EMAX
    return __builtin_elementwise_max(x, z);
#else
    f16x8 r;
#pragma unroll
    for (int j = 0; j < 8; j++) r[j] = x[j] > (f16)0 ? x[j] : (f16)0;
    return r;
#endif
}

// ---------------- P0 (fused): weight prep (fp16 frag tables) + x0/u1/u2 + out zero ----------------
// Blocks 0..15: W2f in 32x32x16 B-frag order:
//   W2f[k][step<16][ctg<8][lane<64][j<8] = W2[k][kk=step*16+(lane>>5)*8+j][n=ctg*32+(lane&31)]
// Blocks 16..32: Wo1f/Wo2f in 16x16x32 B-frag order. Block 33: Wo3f.
// Blocks 34..289: compute_u (u1 in 32x32 A-frag order, u2 row order). Block 290: zero out.
__global__ void prep_and_u(const float* __restrict__ Wm2, const float* __restrict__ Wo1,
                           const float* __restrict__ Wo2, const float* __restrict__ Wo3,
                           f16* __restrict__ W2f, f16* __restrict__ Wo1f,
                           f16* __restrict__ Wo2f, f16* __restrict__ Wo3f,
                           const float* __restrict__ data, const float* __restrict__ act,
                           const float* __restrict__ Wm1, const float* __restrict__ bm1,
                           float* __restrict__ x0, f16* __restrict__ u1f, f16* __restrict__ u2,
                           float* __restrict__ out) {
    __shared__ float tile[32 * 257];
    __shared__ float t3[256 * 25];
    int id = blockIdx.x;
    int tid = threadIdx.x;
    if (id < 16) {
        // W2 -> 32x32x16 B-frag table
        int k = id >> 3, s = id & 7;               // s = 32-row K chunk
        const float* src = Wm2 + k * 65536;
        int kk0 = s * 32;
        for (int t = tid; t < 32 * 256; t += 256) {
            int r = t >> 8, c = t & 255;
            tile[r * 257 + c] = src[(size_t)(kk0 + r) * 256 + c];
        }
        __syncthreads();
#pragma unroll
        for (int it = 0; it < 4; it++) {
            int t = tid + 256 * it;                // 0..1023 = (ls, ctg, l)
            int ls = t >> 9, ctg = (t >> 6) & 7, l = t & 63;
            int n = ctg * 32 + (l & 31);
            int kkl = ls * 16 + ((l >> 5) & 1) * 8;
            H8 o;
#pragma unroll
            for (int j = 0; j < 8; j++) o.h[j] = (f16)tile[(kkl + j) * 257 + n];
            *(uint4*)(W2f + (size_t)k * 131072 + ((size_t)((s * 2 + ls) * 8 + ctg)) * 512 + l * 8) = o.v;
        }
    } else if (id < 33) {
        const float* src; f16* dst; int s, Ksrc;
        if (id < 25) { s = id - 16; src = Wo1; dst = Wo1f; Ksrc = 280; }
        else         { s = id - 25; src = Wo2; dst = Wo2f; Ksrc = 256; }
        int kk0 = s * 32;
        for (int t = tid; t < 32 * 256; t += 256) {
            int r = t >> 8, c = t & 255;
            tile[r * 257 + c] = (kk0 + r < Ksrc) ? src[(size_t)(kk0 + r) * 256 + c] : 0.f;
        }
        __syncthreads();
#pragma unroll
        for (int it = 0; it < 4; it++) {
            int t = tid + 256 * it;                // (nt, l) for 16x16x32 frags
            int nt = t >> 6, l = t & 63;
            int n = nt * 16 + (l & 15), q = l >> 4;
            H8 o;
#pragma unroll
            for (int j = 0; j < 8; j++) o.h[j] = (f16)tile[(q * 8 + j) * 257 + n];
            *(uint4*)(dst + ((size_t)(s * 16 + nt)) * 512 + l * 8) = o.v;
        }
    } else if (id == 33) {
        for (int t = tid; t < 256 * 24; t += 256) {
            int r = t / 24, c = t - r * 24;
            t3[r * 25 + c] = Wo3[t];
        }
        __syncthreads();
#pragma unroll
        for (int it = 0; it < 4; it++) {
            int e = tid + 256 * it;
            int s3 = e >> 7, nt = (e >> 6) & 1, l = e & 63;
            int n = nt * 16 + (l & 15), q = l >> 4;
            H8 o;
#pragma unroll
            for (int j = 0; j < 8; j++) {
                int kk = s3 * 32 + q * 8 + j;
                o.h[j] = (f16)((n < 24) ? t3[kk * 25 + n] : 0.f);
            }
            *(uint4*)(Wo3f + (size_t)e * 8) = o.v;
        }
    } else if (id == 290) {
        if (tid < 64) out[tid] = 0.f;              // out_mlp accumulates via atomicAdd
    } else {
        // ---- compute_u: u1[b,n,k,h] = x0·W1[k][0:24,h]; u2 = x0·W1[k][24:48,h]+b1 ----
        int r0 = (id - 34) * 16;
        int b = r0 >> 6;
        float* xs = tile;
        for (int idx = tid; idx < 16 * 24; idx += 256) {
            int rr = idx / 24, d = idx - rr * 24;
            int r = r0 + rr;
            float v = (d < 16) ? data[(r * 2) * 16 + d]       // t=0 only (output keeps t=0)
                               : act[(r * 2) * 8 + (d - 16)];
            xs[rr * 24 + d] = v;
            x0[r * 24 + d] = v;
        }
        __syncthreads();
        int h = tid;
        float acc[4][16];
#pragma unroll
        for (int q = 0; q < 4; q++)
#pragma unroll
            for (int rr = 0; rr < 16; rr++) acc[q][rr] = 0.f;
#pragma unroll
        for (int d = 0; d < 24; d++) {
            float w10 = Wm1[(0 * 48 + d) * 256 + h];
            float w11 = Wm1[(1 * 48 + d) * 256 + h];
            float w20 = Wm1[(0 * 48 + 24 + d) * 256 + h];
            float w21 = Wm1[(1 * 48 + 24 + d) * 256 + h];
#pragma unroll
            for (int rr = 0; rr < 16; rr++) {
                float x = xs[rr * 24 + d];
                acc[0][rr] += x * w10;
                acc[1][rr] += x * w11;
                acc[2][rr] += x * w20;
                acc[3][rr] += x * w21;
            }
        }
        float bb0 = bm1[h], bb1 = bm1[256 + h];
        // u1f: 32x32 A-frag order: entry = (step*2+rt)*64 + lane, j
        int step = h >> 4, j = h & 7, lanehalf = (h >> 3) & 1;
#pragma unroll
        for (int rr = 0; rr < 16; rr++) {
            int r = r0 + rr;
            int row = r & 63;
            int entry = (step * 2 + (row >> 5)) * 64 + ((row & 31) | (lanehalf << 5));
            u1f[((size_t)(b * 2 + 0)) * 16384 + entry * 8 + j] = (f16)acc[0][rr];
            u1f[((size_t)(b * 2 + 1)) * 16384 + entry * 8 + j] = (f16)acc[1][rr];
            u2[((size_t)r * 2 + 0) * 256 + h] = (f16)(acc[2][rr] + bb0);
            u2[((size_t)r * 2 + 1) * 256 + h] = (f16)(acc[3][rr] + bb1);
        }
    }
}

// ---------------- K3: edge MLP layer-2 + weighted aggregate ----------------
// block = (b, 4 receivers). u1 frags staged in LDS once per k (shared by 4 i's);
// i-loop is barrier-free (A built inline per wave). 32x32x16 MFMA, bias folded.
// launch_bounds(256,4): total unified budget 128/wave (64 acc + ~54 temps) ->
// 4 blocks/CU (grid 1024 = exact full residency). unroll 2 caps live B-loads.
// Spill tripwire: WRITE_SIZE must stay ~4 MB (R6 spilled 585 MB at tighter budget).
__global__ __launch_bounds__(256, 4) void edge_kernel(
    const f16* __restrict__ u1f, const f16* __restrict__ u2, const float* __restrict__ edges,
    const f16* __restrict__ W2f, const float* __restrict__ bm2, float* __restrict__ agg) {
    int blk = blockIdx.x;
    int b = blk >> 4;
    int i0 = (blk & 15) * 4;
    __shared__ __align__(16) f16 u1s[16384];      // 32 KB: [step<16][rt<2][lane<64][8]
    __shared__ __align__(16) f16 u2s[4 * 256];    // 2 KB
    __shared__ float w_s[4 * 64];                 // 1 KB
    __shared__ float aggs[4 * 256];               // 4 KB   (39936 B total -> 4 blocks/CU)
    int tid = threadIdx.x;
    int lane = tid & 63, wave = tid >> 6;
    const int l5 = lane >> 5;                     // 0/1: K-half
    const int colBase = wave * 64;

#pragma unroll
    for (int t = tid; t < 1024; t += 256) aggs[t] = 0.f;

#pragma unroll 1
    for (int k = 0; k < 2; k++) {
        __syncthreads();                          // waves done with u1s/u2s of prev k
        {   // stage u1 frags (32 KB, straight copy in frag order)
            const uint4* src = (const uint4*)(u1f + ((size_t)(b * 2 + k)) * 16384);
            uint4* dst = (uint4*)u1s;
#pragma unroll
            for (int it = 0; it < 8; it++) dst[tid + 256 * it] = src[tid + 256 * it];
        }
        if (tid < 128) {                          // stage u2 rows (4 x 256 f16)
            int ii = tid >> 5, u4 = tid & 31;
            *(uint4*)&u2s[ii * 256 + u4 * 8] =
                *(const uint4*)&u2[((size_t)(b * 64 + i0 + ii) * 2 + k) * 256 + u4 * 8];
        }
        {   // stage edge weights (4 x 64)
            int ii = tid >> 6, j = tid & 63;
            int ia = i0 + ii;
            float w = 0.f;
            if (j != ia) {
                int jj = j - (j > ia ? 1 : 0);
                w = edges[((size_t)b * 4032 + (size_t)ia * 63 + jj) * 2 + k];
            }
            w_s[tid] = w;
        }
        float bb[2];
#pragma unroll
        for (int ct = 0; ct < 2; ct++) bb[ct] = bm2[k * 256 + colBase + ct * 32 + (lane & 31)];
        __syncthreads();

        const f16* Wkb = W2f + (size_t)k * 131072 + (size_t)(wave * 2) * 512 + lane * 8;

#pragma unroll 1
        for (int il = 0; il < 4; il++) {
            floatx16 acc[2][2];                   // [rt][ct], bias pre-folded
#pragma unroll
            for (int rt = 0; rt < 2; rt++)
#pragma unroll
                for (int ct = 0; ct < 2; ct++)
#pragma unroll
                    for (int q = 0; q < 16; q++) acc[rt][ct][q] = bb[ct];

            const f16* pu2 = &u2s[il * 256 + l5 * 8];
#pragma unroll 2
            for (int step = 0; step < 16; step++) {
                f16x8 bfr[2];
#pragma unroll
                for (int ct = 0; ct < 2; ct++)
                    bfr[ct] = *(const f16x8*)(Wkb + (size_t)(step * 8 + ct) * 512);
                f16x8 uv = *(const f16x8*)(pu2 + step * 16);
                f16x8 af[2];
#pragma unroll
                for (int rt = 0; rt < 2; rt++) {
                    f16x8 u1v = *(const f16x8*)&u1s[((step * 2 + rt) * 64 + lane) * 8];
                    af[rt] = relu8(u1v + uv);
                }
#pragma unroll
                for (int rt = 0; rt < 2; rt++)
#pragma unroll
                    for (int ct = 0; ct < 2; ct++)
                        acc[rt][ct] = __builtin_amdgcn_mfma_f32_32x32x16_f16(
                            af[rt], bfr[ct], acc[rt][ct], 0, 0, 0);
            }
            // epilogue: sum_j relu(C)*w.  C: col=lane&31, row=(reg&3)+8*(reg>>2)+4*(lane>>5)
#pragma unroll
            for (int ct = 0; ct < 2; ct++) {
                float p = 0.f;
#pragma unroll
                for (int rt = 0; rt < 2; rt++) {
                    const float* wr = &w_s[il * 64 + rt * 32 + l5 * 4];
#pragma unroll
                    for (int g = 0; g < 4; g++) {
                        float4 wv = *(const float4*)(wr + g * 8);
                        p += fmaxf(acc[rt][ct][g * 4 + 0], 0.f) * wv.x;
                        p += fmaxf(acc[rt][ct][g * 4 + 1], 0.f) * wv.y;
                        p += fmaxf(acc[rt][ct][g * 4 + 2], 0.f) * wv.z;
                        p += fmaxf(acc[rt][ct][g * 4 + 3], 0.f) * wv.w;
                    }
                }
                p += __shfl_xor(p, 32, 64);
                if (l5 == 0) aggs[il * 256 + colBase + ct * 32 + lane] += p;  // wave-private cols
            }
        }
    }
    __syncthreads();
#pragma unroll
    for (int t = tid; t < 1024; t += 256)
        agg[((size_t)(b * 64 + i0 + (t >> 8))) * 256 + (t & 255)] = aggs[t];
}

// ---------------- K4: out-MLP, 4 blocks per batch (M=16 rows each) ----------------
__global__ void out_mlp(const float* __restrict__ x0, const float* __restrict__ agg,
                        const f16* __restrict__ Wo1f, const f16* __restrict__ Wo2f,
                        const f16* __restrict__ Wo3f,
                        const float* __restrict__ bo1, const float* __restrict__ bo2,
                        const float* __restrict__ bo3,
                        const float* __restrict__ Wq2, const float* __restrict__ bq2,
                        const float* __restrict__ Wq3, const float* __restrict__ bq3,
                        float* __restrict__ out) {
    int blk = blockIdx.x;
    int b = blk >> 2, n0 = (blk & 3) * 16;
    int tid = threadIdx.x;
    int lane = tid & 63, wave = tid >> 6;
    const int colBase = wave * 64;
    const int lhi = lane >> 4;
    __shared__ __align__(16) f16 A1f[9 * 64 * 8];
    __shared__ __align__(16) f16 A2f[8 * 64 * 8];
    __shared__ __align__(16) f16 h2f[8 * 64 * 8];
    __shared__ float pq[16][2];

    for (int t = tid; t < 576; t += 256) {
        int lane_f = t & 63, s = t >> 6;
        int m = n0 + (lane_f & 15);
        int c0 = s * 32 + (lane_f >> 4) * 8;
        float vals[8];
        if (c0 < 24) {
            const float4* xr = (const float4*)(x0 + (b * 64 + m) * 24 + c0);
            float4 a = xr[0], c = xr[1];
            vals[0] = a.x; vals[1] = a.y; vals[2] = a.z; vals[3] = a.w;
            vals[4] = c.x; vals[5] = c.y; vals[6] = c.z; vals[7] = c.w;
        } else if (c0 < 280) {
            const float4* ar = (const float4*)(agg + ((size_t)(b * 64 + m)) * 256 + (c0 - 24));
            float4 a = ar[0], c = ar[1];
            vals[0] = a.x; vals[1] = a.y; vals[2] = a.z; vals[3] = a.w;
            vals[4] = c.x; vals[5] = c.y; vals[6] = c.z; vals[7] = c.w;
        } else {
#pragma unroll
            for (int q = 0; q < 8; q++) vals[q] = 0.f;
        }
        H8 o;
#pragma unroll
        for (int q = 0; q < 8; q++) o.h[q] = (f16)vals[q];
        *(uint4*)(&A1f[t * 8]) = o.v;
    }
    __syncthreads();

    floatx4 acc[4];
#pragma unroll
    for (int ct = 0; ct < 4; ct++)
#pragma unroll
        for (int q = 0; q < 4; q++) acc[ct][q] = 0.f;
#pragma unroll
    for (int step = 0; step < 9; step++) {
        f16x8 af = *(const f16x8*)(&A1f[(step * 64 + lane) * 8]);
#pragma unroll
        for (int ct = 0; ct < 4; ct++) {
            f16x8 bfr = *(const f16x8*)(Wo1f + ((size_t)(step * 16 + wave * 4 + ct)) * 512 + lane * 8);
            acc[ct] = __builtin_amdgcn_mfma_f32_16x16x32_f16(af, bfr, acc[ct], 0, 0, 0);
        }
    }
#pragma unroll
    for (int ct = 0; ct < 4; ct++) {
        int col = colBase + ct * 16 + (lane & 15);
        float bbv = bo1[col];
        int s2 = col >> 5, jj = col & 7, lf_hi = ((col >> 3) & 3) << 4;
#pragma unroll
        for (int reg = 0; reg < 4; reg++) {
            int row = lhi * 4 + reg;
            A2f[(s2 * 64 + (row | lf_hi)) * 8 + jj] = (f16)fmaxf(acc[ct][reg] + bbv, 0.f);
        }
    }
    __syncthreads();

#pragma unroll
    for (int ct = 0; ct < 4; ct++)
#pragma unroll
        for (int q = 0; q < 4; q++) acc[ct][q] = 0.f;
#pragma unroll
    for (int step = 0; step < 8; step++) {
        f16x8 af = *(const f16x8*)(&A2f[(step * 64 + lane) * 8]);
#pragma unroll
        for (int ct = 0; ct < 4; ct++) {
            f16x8 bfr = *(const f16x8*)(Wo2f + ((size_t)(step * 16 + wave * 4 + ct)) * 512 + lane * 8);
            acc[ct] = __builtin_amdgcn_mfma_f32_16x16x32_f16(af, bfr, acc[ct], 0, 0, 0);
        }
    }
#pragma unroll
    for (int ct = 0; ct < 4; ct++) {
        int col = colBase + ct * 16 + (lane & 15);
        float bbv = bo2[col];
        int s2 = col >> 5, jj = col & 7, lf_hi = ((col >> 3) & 3) << 4;
#pragma unroll
        for (int reg = 0; reg < 4; reg++) {
            int row = lhi * 4 + reg;
            h2f[(s2 * 64 + (row | lf_hi)) * 8 + jj] = (f16)fmaxf(acc[ct][reg] + bbv, 0.f);
        }
    }
    __syncthreads();

    if (wave < 2) {
        floatx4 acc3;
#pragma unroll
        for (int q = 0; q < 4; q++) acc3[q] = 0.f;
#pragma unroll
        for (int step = 0; step < 8; step++) {
            f16x8 af = *(const f16x8*)(&h2f[(step * 64 + lane) * 8]);
            f16x8 bfr = *(const f16x8*)(Wo3f + ((size_t)(step * 2 + wave)) * 512 + lane * 8);
            acc3 = __builtin_amdgcn_mfma_f32_16x16x32_f16(af, bfr, acc3, 0, 0, 0);
        }
        int col = wave * 16 + (lane & 15);
        float pr[4];
#pragma unroll
        for (int reg = 0; reg < 4; reg++) {
            float p = 0.f;
            if (col < 24) {
                int row = lhi * 4 + reg;
                float val = acc3[reg] + bo3[col] + x0[(b * 64 + n0 + row) * 24 + col];
                p = val * Wq2[col];
            }
            pr[reg] = p;
        }
#pragma unroll
        for (int off = 1; off <= 8; off <<= 1)
#pragma unroll
            for (int reg = 0; reg < 4; reg++) pr[reg] += __shfl_xor(pr[reg], off, 64);
        if ((lane & 15) == 0) {
#pragma unroll
            for (int reg = 0; reg < 4; reg++) pq[lhi * 4 + reg][wave] = pr[reg];
        }
    }
    __syncthreads();
    if (tid == 0) {
        float s = ((blk & 3) == 0) ? bq3[0] : 0.f;
#pragma unroll
        for (int r = 0; r < 16; r++)
            s += (pq[r][0] + pq[r][1] + bq2[0]) * Wq3[n0 + r];
        atomicAdd(out + b, s);
    }
}

extern "C" void kernel_launch(void* const* d_in, const int* in_sizes, int n_in,
                              void* d_out, int out_size, void* d_ws, size_t ws_size,
                              hipStream_t stream) {
    const float* data = (const float*)d_in[0];
    const float* act  = (const float*)d_in[1];
    const float* edges = (const float*)d_in[2];
    // d_in[3] rel_rec, d_in[4] rel_send, d_in[5] prediction_steps: structure hardcoded (steps=1)
    const float* Wm1 = (const float*)d_in[6];
    const float* bm1 = (const float*)d_in[7];
    const float* Wm2 = (const float*)d_in[8];
    const float* bm2 = (const float*)d_in[9];
    const float* Wo1 = (const float*)d_in[10];
    const float* bo1 = (const float*)d_in[11];
    const float* Wo2 = (const float*)d_in[12];
    const float* bo2 = (const float*)d_in[13];
    const float* Wo3 = (const float*)d_in[14];
    const float* bo3 = (const float*)d_in[15];
    const float* Wq2 = (const float*)d_in[16];
    const float* bq2 = (const float*)d_in[17];
    const float* Wq3 = (const float*)d_in[18];
    const float* bq3 = (const float*)d_in[19];
    float* out = (float*)d_out;

    char* ws = (char*)d_ws;
    size_t off = 0;
    auto carve = [&](size_t bytes) -> void* {
        void* p = ws + off;
        off += (bytes + 255) & ~(size_t)255;
        return p;
    };
    f16*   u1f  = (f16*)carve((size_t)64 * 2 * 16384 * 2);      // 4 MB, 32x32 A-frag order
    f16*   u2   = (f16*)carve((size_t)64 * 64 * 2 * 256 * 2);   // 4 MB, row order
    float* x0   = (float*)carve((size_t)64 * 64 * 24 * 4);
    float* agg  = (float*)carve((size_t)64 * 64 * 256 * 4);     // 4 MB
    f16*   W2f  = (f16*)carve((size_t)2 * 131072 * 2);          // 512 KB, 32x32 B-frag order
    f16*   Wo1f = (f16*)carve((size_t)9 * 16 * 64 * 8 * 2);
    f16*   Wo2f = (f16*)carve((size_t)8 * 16 * 64 * 8 * 2);
    f16*   Wo3f = (f16*)carve((size_t)8 * 2 * 64 * 8 * 2);

    prep_and_u<<<dim3(291), dim3(256), 0, stream>>>(Wm2, Wo1, Wo2, Wo3, W2f, Wo1f, Wo2f, Wo3f,
                                                    data, act, Wm1, bm1, x0, u1f, u2, out);
    edge_kernel<<<dim3(1024), dim3(256), 0, stream>>>(u1f, u2, edges, W2f, bm2, agg);
    out_mlp<<<dim3(256), dim3(256), 0, stream>>>(x0, agg, Wo1f, Wo2f, Wo3f, bo1, bo2, bo3,
                                                 Wq2, bq2, Wq3, bq3, out);
}

// Round 10
// 198.493 us; speedup vs baseline: 3.5205x; 1.0041x over previous
//
#include <hip/hip_runtime.h>

typedef _Float16 f16;
typedef __attribute__((ext_vector_type(8))) _Float16 f16x8;
typedef __attribute__((ext_vector_type(4))) float floatx4;
typedef __attribute__((ext_vector_type(16))) float floatx16;

union H8 { f16 h[8]; uint4 v; };

#if defined(__has_builtin)
#if __has_builtin(__builtin_elementwise_max)
#define HAVE_EMAX 1
#endif
#endif

__device__ __forceinline__ f16x8 relu8(f16x8 x) {
    f16x8 z = {};
#ifdef HAVE_EMAX
    return __builtin_elementwise_max(x, z);
#else
    f16x8 r;
#pragma unroll
    for (int j = 0; j < 8; j++) r[j] = x[j] > (f16)0 ? x[j] : (f16)0;
    return r;
#endif
}

// ---------------- P0 (fused): weight prep (fp16 frag tables) + x0/u1/u2 + out zero ----------------
// Blocks 0..15: W2f in 32x32x16 B-frag order:
//   W2f[k][step<16][ctg<8][lane<64][j<8] = W2[k][kk=step*16+(lane>>5)*8+j][n=ctg*32+(lane&31)]
// Blocks 16..32: Wo1f/Wo2f in 16x16x32 B-frag order. Block 33: Wo3f.
// Blocks 34..289: compute_u (u1 in 32x32 A-frag order, u2 row order). Block 290: zero out.
__global__ void prep_and_u(const float* __restrict__ Wm2, const float* __restrict__ Wo1,
                           const float* __restrict__ Wo2, const float* __restrict__ Wo3,
                           f16* __restrict__ W2f, f16* __restrict__ Wo1f,
                           f16* __restrict__ Wo2f, f16* __restrict__ Wo3f,
                           const float* __restrict__ data, const float* __restrict__ act,
                           const float* __restrict__ Wm1, const float* __restrict__ bm1,
                           float* __restrict__ x0, f16* __restrict__ u1f, f16* __restrict__ u2,
                           float* __restrict__ out) {
    __shared__ float tile[32 * 257];
    __shared__ float t3[256 * 25];
    int id = blockIdx.x;
    int tid = threadIdx.x;
    if (id < 16) {
        // W2 -> 32x32x16 B-frag table
        int k = id >> 3, s = id & 7;               // s = 32-row K chunk
        const float* src = Wm2 + k * 65536;
        int kk0 = s * 32;
        for (int t = tid; t < 32 * 256; t += 256) {
            int r = t >> 8, c = t & 255;
            tile[r * 257 + c] = src[(size_t)(kk0 + r) * 256 + c];
        }
        __syncthreads();
#pragma unroll
        for (int it = 0; it < 4; it++) {
            int t = tid + 256 * it;                // 0..1023 = (ls, ctg, l)
            int ls = t >> 9, ctg = (t >> 6) & 7, l = t & 63;
            int n = ctg * 32 + (l & 31);
            int kkl = ls * 16 + ((l >> 5) & 1) * 8;
            H8 o;
#pragma unroll
            for (int j = 0; j < 8; j++) o.h[j] = (f16)tile[(kkl + j) * 257 + n];
            *(uint4*)(W2f + (size_t)k * 131072 + ((size_t)((s * 2 + ls) * 8 + ctg)) * 512 + l * 8) = o.v;
        }
    } else if (id < 33) {
        const float* src; f16* dst; int s, Ksrc;
        if (id < 25) { s = id - 16; src = Wo1; dst = Wo1f; Ksrc = 280; }
        else         { s = id - 25; src = Wo2; dst = Wo2f; Ksrc = 256; }
        int kk0 = s * 32;
        for (int t = tid; t < 32 * 256; t += 256) {
            int r = t >> 8, c = t & 255;
            tile[r * 257 + c] = (kk0 + r < Ksrc) ? src[(size_t)(kk0 + r) * 256 + c] : 0.f;
        }
        __syncthreads();
#pragma unroll
        for (int it = 0; it < 4; it++) {
            int t = tid + 256 * it;                // (nt, l) for 16x16x32 frags
            int nt = t >> 6, l = t & 63;
            int n = nt * 16 + (l & 15), q = l >> 4;
            H8 o;
#pragma unroll
            for (int j = 0; j < 8; j++) o.h[j] = (f16)tile[(q * 8 + j) * 257 + n];
            *(uint4*)(dst + ((size_t)(s * 16 + nt)) * 512 + l * 8) = o.v;
        }
    } else if (id == 33) {
        for (int t = tid; t < 256 * 24; t += 256) {
            int r = t / 24, c = t - r * 24;
            t3[r * 25 + c] = Wo3[t];
        }
        __syncthreads();
#pragma unroll
        for (int it = 0; it < 4; it++) {
            int e = tid + 256 * it;
            int s3 = e >> 7, nt = (e >> 6) & 1, l = e & 63;
            int n = nt * 16 + (l & 15), q = l >> 4;
            H8 o;
#pragma unroll
            for (int j = 0; j < 8; j++) {
                int kk = s3 * 32 + q * 8 + j;
                o.h[j] = (f16)((n < 24) ? t3[kk * 25 + n] : 0.f);
            }
            *(uint4*)(Wo3f + (size_t)e * 8) = o.v;
        }
    } else if (id == 290) {
        if (tid < 64) out[tid] = 0.f;              // out_mlp accumulates via atomicAdd
    } else {
        // ---- compute_u: u1[b,n,k,h] = x0·W1[k][0:24,h]; u2 = x0·W1[k][24:48,h]+b1 ----
        int r0 = (id - 34) * 16;
        int b = r0 >> 6;
        float* xs = tile;
        for (int idx = tid; idx < 16 * 24; idx += 256) {
            int rr = idx / 24, d = idx - rr * 24;
            int r = r0 + rr;
            float v = (d < 16) ? data[(r * 2) * 16 + d]       // t=0 only (output keeps t=0)
                               : act[(r * 2) * 8 + (d - 16)];
            xs[rr * 24 + d] = v;
            x0[r * 24 + d] = v;
        }
        __syncthreads();
        int h = tid;
        float acc[4][16];
#pragma unroll
        for (int q = 0; q < 4; q++)
#pragma unroll
            for (int rr = 0; rr < 16; rr++) acc[q][rr] = 0.f;
#pragma unroll
        for (int d = 0; d < 24; d++) {
            float w10 = Wm1[(0 * 48 + d) * 256 + h];
            float w11 = Wm1[(1 * 48 + d) * 256 + h];
            float w20 = Wm1[(0 * 48 + 24 + d) * 256 + h];
            float w21 = Wm1[(1 * 48 + 24 + d) * 256 + h];
#pragma unroll
            for (int rr = 0; rr < 16; rr++) {
                float x = xs[rr * 24 + d];
                acc[0][rr] += x * w10;
                acc[1][rr] += x * w11;
                acc[2][rr] += x * w20;
                acc[3][rr] += x * w21;
            }
        }
        float bb0 = bm1[h], bb1 = bm1[256 + h];
        // u1f: 32x32 A-frag order: entry = (step*2+rt)*64 + lane, j
        int step = h >> 4, j = h & 7, lanehalf = (h >> 3) & 1;
#pragma unroll
        for (int rr = 0; rr < 16; rr++) {
            int r = r0 + rr;
            int row = r & 63;
            int entry = (step * 2 + (row >> 5)) * 64 + ((row & 31) | (lanehalf << 5));
            u1f[((size_t)(b * 2 + 0)) * 16384 + entry * 8 + j] = (f16)acc[0][rr];
            u1f[((size_t)(b * 2 + 1)) * 16384 + entry * 8 + j] = (f16)acc[1][rr];
            u2[((size_t)r * 2 + 0) * 256 + h] = (f16)(acc[2][rr] + bb0);
            u2[((size_t)r * 2 + 1) * 256 + h] = (f16)(acc[3][rr] + bb1);
        }
    }
}

// ---------------- K3: edge MLP layer-2 + weighted aggregate ----------------
// block = (b, 4 receivers). u1 frags in LDS once per k (shared by 4 i's); i-loop
// barrier-free. Step loop is MANUALLY SOFTWARE-PIPELINED: step+1's B (L2) and
// A/u2 (LDS) fragments are prefetched before step's relu+MFMA consume the current
// ones; last-step prefetch over-reads into adjacent allocated ws/LDS (harmless,
// branch-free). Lean live set (~115 regs incl 64 acc) to give (256,4) a real
// shot at 4 blocks/CU. Spill tripwire: WRITE_SIZE must stay ~4 MB.
__global__ __launch_bounds__(256, 4) void edge_kernel(
    const f16* __restrict__ u1f, const f16* __restrict__ u2, const float* __restrict__ edges,
    const f16* __restrict__ W2f, const float* __restrict__ bm2, float* __restrict__ agg) {
    int blk = blockIdx.x;
    int b = blk >> 4;
    int i0 = (blk & 15) * 4;
    __shared__ __align__(16) f16 u1s[16384];      // 32 KB: [step<16][rt<2][lane<64][8]
    __shared__ __align__(16) f16 u2s[4 * 256];    // 2 KB
    __shared__ float w_s[4 * 64];                 // 1 KB
    __shared__ float aggs[4 * 256];               // 4 KB   (39936 B total)
    int tid = threadIdx.x;
    int lane = tid & 63, wave = tid >> 6;
    const int l5 = lane >> 5;                     // 0/1: K-half
    const int colBase = wave * 64;

#pragma unroll
    for (int t = tid; t < 1024; t += 256) aggs[t] = 0.f;

#pragma unroll 1
    for (int k = 0; k < 2; k++) {
        __syncthreads();                          // waves done with u1s/u2s of prev k
        {   // stage u1 frags (32 KB, straight copy in frag order)
            const uint4* src = (const uint4*)(u1f + ((size_t)(b * 2 + k)) * 16384);
            uint4* dst = (uint4*)u1s;
#pragma unroll
            for (int it = 0; it < 8; it++) dst[tid + 256 * it] = src[tid + 256 * it];
        }
        if (tid < 128) {                          // stage u2 rows (4 x 256 f16)
            int ii = tid >> 5, u4 = tid & 31;
            *(uint4*)&u2s[ii * 256 + u4 * 8] =
                *(const uint4*)&u2[((size_t)(b * 64 + i0 + ii) * 2 + k) * 256 + u4 * 8];
        }
        {   // stage edge weights (4 x 64)
            int ii = tid >> 6, j = tid & 63;
            int ia = i0 + ii;
            float w = 0.f;
            if (j != ia) {
                int jj = j - (j > ia ? 1 : 0);
                w = edges[((size_t)b * 4032 + (size_t)ia * 63 + jj) * 2 + k];
            }
            w_s[tid] = w;
        }
        float bb[2];
#pragma unroll
        for (int ct = 0; ct < 2; ct++) bb[ct] = bm2[k * 256 + colBase + ct * 32 + (lane & 31)];
        __syncthreads();

        const f16* Wkb = W2f + (size_t)k * 131072 + (size_t)(wave * 2) * 512 + lane * 8;
        const f16* u1l = &u1s[lane * 8];

#pragma unroll 1
        for (int il = 0; il < 4; il++) {
            floatx16 acc[2][2];                   // [rt][ct], bias pre-folded
#pragma unroll
            for (int rt = 0; rt < 2; rt++)
#pragma unroll
                for (int ct = 0; ct < 2; ct++)
#pragma unroll
                    for (int q = 0; q < 16; q++) acc[rt][ct][q] = bb[ct];

            const f16* pu2 = &u2s[il * 256 + l5 * 8];
            // pipeline prologue: step 0 fragments
            f16x8 b0 = *(const f16x8*)(Wkb);
            f16x8 b1 = *(const f16x8*)(Wkb + 512);
            f16x8 a0 = *(const f16x8*)(u1l);
            f16x8 a1 = *(const f16x8*)(u1l + 512);
            f16x8 uv = *(const f16x8*)(pu2);
#pragma unroll 1
            for (int step = 0; step < 16; step++) {
                // prefetch step+1 (last iter over-reads into allocated ws/LDS: harmless)
                f16x8 nb0 = *(const f16x8*)(Wkb + (size_t)(step + 1) * 4096);
                f16x8 nb1 = *(const f16x8*)(Wkb + (size_t)(step + 1) * 4096 + 512);
                f16x8 na0 = *(const f16x8*)(u1l + (step + 1) * 1024);
                f16x8 na1 = *(const f16x8*)(u1l + (step + 1) * 1024 + 512);
                f16x8 nuv = *(const f16x8*)(pu2 + (step + 1) * 16);
                f16x8 af0 = relu8(a0 + uv);
                f16x8 af1 = relu8(a1 + uv);
                acc[0][0] = __builtin_amdgcn_mfma_f32_32x32x16_f16(af0, b0, acc[0][0], 0, 0, 0);
                acc[1][0] = __builtin_amdgcn_mfma_f32_32x32x16_f16(af1, b0, acc[1][0], 0, 0, 0);
                acc[0][1] = __builtin_amdgcn_mfma_f32_32x32x16_f16(af0, b1, acc[0][1], 0, 0, 0);
                acc[1][1] = __builtin_amdgcn_mfma_f32_32x32x16_f16(af1, b1, acc[1][1], 0, 0, 0);
                b0 = nb0; b1 = nb1; a0 = na0; a1 = na1; uv = nuv;
            }
            // epilogue: sum_j relu(C)*w.  C: col=lane&31, row=(reg&3)+8*(reg>>2)+4*(lane>>5)
#pragma unroll
            for (int ct = 0; ct < 2; ct++) {
                float p = 0.f;
#pragma unroll
                for (int rt = 0; rt < 2; rt++) {
                    const float* wr = &w_s[il * 64 + rt * 32 + l5 * 4];
#pragma unroll
                    for (int g = 0; g < 4; g++) {
                        float4 wv = *(const float4*)(wr + g * 8);
                        p += fmaxf(acc[rt][ct][g * 4 + 0], 0.f) * wv.x;
                        p += fmaxf(acc[rt][ct][g * 4 + 1], 0.f) * wv.y;
                        p += fmaxf(acc[rt][ct][g * 4 + 2], 0.f) * wv.z;
                        p += fmaxf(acc[rt][ct][g * 4 + 3], 0.f) * wv.w;
                    }
                }
                p += __shfl_xor(p, 32, 64);
                if (l5 == 0) aggs[il * 256 + colBase + ct * 32 + lane] += p;  // wave-private cols
            }
        }
    }
    __syncthreads();
#pragma unroll
    for (int t = tid; t < 1024; t += 256)
        agg[((size_t)(b * 64 + i0 + (t >> 8))) * 256 + (t & 255)] = aggs[t];
}

// ---------------- K4: out-MLP, 4 blocks per batch (M=16 rows each) ----------------
__global__ void out_mlp(const float* __restrict__ x0, const float* __restrict__ agg,
                        const f16* __restrict__ Wo1f, const f16* __restrict__ Wo2f,
                        const f16* __restrict__ Wo3f,
                        const float* __restrict__ bo1, const float* __restrict__ bo2,
                        const float* __restrict__ bo3,
                        const float* __restrict__ Wq2, const float* __restrict__ bq2,
                        const float* __restrict__ Wq3, const float* __restrict__ bq3,
                        float* __restrict__ out) {
    int blk = blockIdx.x;
    int b = blk >> 2, n0 = (blk & 3) * 16;
    int tid = threadIdx.x;
    int lane = tid & 63, wave = tid >> 6;
    const int colBase = wave * 64;
    const int lhi = lane >> 4;
    __shared__ __align__(16) f16 A1f[9 * 64 * 8];
    __shared__ __align__(16) f16 A2f[8 * 64 * 8];
    __shared__ __align__(16) f16 h2f[8 * 64 * 8];
    __shared__ float pq[16][2];

    for (int t = tid; t < 576; t += 256) {
        int lane_f = t & 63, s = t >> 6;
        int m = n0 + (lane_f & 15);
        int c0 = s * 32 + (lane_f >> 4) * 8;
        float vals[8];
        if (c0 < 24) {
            const float4* xr = (const float4*)(x0 + (b * 64 + m) * 24 + c0);
            float4 a = xr[0], c = xr[1];
            vals[0] = a.x; vals[1] = a.y; vals[2] = a.z; vals[3] = a.w;
            vals[4] = c.x; vals[5] = c.y; vals[6] = c.z; vals[7] = c.w;
        } else if (c0 < 280) {
            const float4* ar = (const float4*)(agg + ((size_t)(b * 64 + m)) * 256 + (c0 - 24));
            float4 a = ar[0], c = ar[1];
            vals[0] = a.x; vals[1] = a.y; vals[2] = a.z; vals[3] = a.w;
            vals[4] = c.x; vals[5] = c.y; vals[6] = c.z; vals[7] = c.w;
        } else {
#pragma unroll
            for (int q = 0; q < 8; q++) vals[q] = 0.f;
        }
        H8 o;
#pragma unroll
        for (int q = 0; q < 8; q++) o.h[q] = (f16)vals[q];
        *(uint4*)(&A1f[t * 8]) = o.v;
    }
    __syncthreads();

    floatx4 acc[4];
#pragma unroll
    for (int ct = 0; ct < 4; ct++)
#pragma unroll
        for (int q = 0; q < 4; q++) acc[ct][q] = 0.f;
#pragma unroll
    for (int step = 0; step < 9; step++) {
        f16x8 af = *(const f16x8*)(&A1f[(step * 64 + lane) * 8]);
#pragma unroll
        for (int ct = 0; ct < 4; ct++) {
            f16x8 bfr = *(const f16x8*)(Wo1f + ((size_t)(step * 16 + wave * 4 + ct)) * 512 + lane * 8);
            acc[ct] = __builtin_amdgcn_mfma_f32_16x16x32_f16(af, bfr, acc[ct], 0, 0, 0);
        }
    }
#pragma unroll
    for (int ct = 0; ct < 4; ct++) {
        int col = colBase + ct * 16 + (lane & 15);
        float bbv = bo1[col];
        int s2 = col >> 5, jj = col & 7, lf_hi = ((col >> 3) & 3) << 4;
#pragma unroll
        for (int reg = 0; reg < 4; reg++) {
            int row = lhi * 4 + reg;
            A2f[(s2 * 64 + (row | lf_hi)) * 8 + jj] = (f16)fmaxf(acc[ct][reg] + bbv, 0.f);
        }
    }
    __syncthreads();

#pragma unroll
    for (int ct = 0; ct < 4; ct++)
#pragma unroll
        for (int q = 0; q < 4; q++) acc[ct][q] = 0.f;
#pragma unroll
    for (int step = 0; step < 8; step++) {
        f16x8 af = *(const f16x8*)(&A2f[(step * 64 + lane) * 8]);
#pragma unroll
        for (int ct = 0; ct < 4; ct++) {
            f16x8 bfr = *(const f16x8*)(Wo2f + ((size_t)(step * 16 + wave * 4 + ct)) * 512 + lane * 8);
            acc[ct] = __builtin_amdgcn_mfma_f32_16x16x32_f16(af, bfr, acc[ct], 0, 0, 0);
        }
    }
#pragma unroll
    for (int ct = 0; ct < 4; ct++) {
        int col = colBase + ct * 16 + (lane & 15);
        float bbv = bo2[col];
        int s2 = col >> 5, jj = col & 7, lf_hi = ((col >> 3) & 3) << 4;
#pragma unroll
        for (int reg = 0; reg < 4; reg++) {
            int row = lhi * 4 + reg;
            h2f[(s2 * 64 + (row | lf_hi)) * 8 + jj] = (f16)fmaxf(acc[ct][reg] + bbv, 0.f);
        }
    }
    __syncthreads();

    if (wave < 2) {
        floatx4 acc3;
#pragma unroll
        for (int q = 0; q < 4; q++) acc3[q] = 0.f;
#pragma unroll
        for (int step = 0; step < 8; step++) {
            f16x8 af = *(const f16x8*)(&h2f[(step * 64 + lane) * 8]);
            f16x8 bfr = *(const f16x8*)(Wo3f + ((size_t)(step * 2 + wave)) * 512 + lane * 8);
            acc3 = __builtin_amdgcn_mfma_f32_16x16x32_f16(af, bfr, acc3, 0, 0, 0);
        }
        int col = wave * 16 + (lane & 15);
        float pr[4];
#pragma unroll
        for (int reg = 0; reg < 4; reg++) {
            float p = 0.f;
            if (col < 24) {
                int row = lhi * 4 + reg;
                float val = acc3[reg] + bo3[col] + x0[(b * 64 + n0 + row) * 24 + col];
                p = val * Wq2[col];
            }
            pr[reg] = p;
        }
#pragma unroll
        for (int off = 1; off <= 8; off <<= 1)
#pragma unroll
            for (int reg = 0; reg < 4; reg++) pr[reg] += __shfl_xor(pr[reg], off, 64);
        if ((lane & 15) == 0) {
#pragma unroll
            for (int reg = 0; reg < 4; reg++) pq[lhi * 4 + reg][wave] = pr[reg];
        }
    }
    __syncthreads();
    if (tid == 0) {
        float s = ((blk & 3) == 0) ? bq3[0] : 0.f;
#pragma unroll
        for (int r = 0; r < 16; r++)
            s += (pq[r][0] + pq[r][1] + bq2[0]) * Wq3[n0 + r];
        atomicAdd(out + b, s);
    }
}

extern "C" void kernel_launch(void* const* d_in, const int* in_sizes, int n_in,
                              void* d_out, int out_size, void* d_ws, size_t ws_size,
                              hipStream_t stream) {
    const float* data = (const float*)d_in[0];
    const float* act  = (const float*)d_in[1];
    const float* edges = (const float*)d_in[2];
    // d_in[3] rel_rec, d_in[4] rel_send, d_in[5] prediction_steps: structure hardcoded (steps=1)
    const float* Wm1 = (const float*)d_in[6];
    const float* bm1 = (const float*)d_in[7];
    const float* Wm2 = (const float*)d_in[8];
    const float* bm2 = (const float*)d_in[9];
    const float* Wo1 = (const float*)d_in[10];
    const float* bo1 = (const float*)d_in[11];
    const float* Wo2 = (const float*)d_in[12];
    const float* bo2 = (const float*)d_in[13];
    const float* Wo3 = (const float*)d_in[14];
    const float* bo3 = (const float*)d_in[15];
    const float* Wq2 = (const float*)d_in[16];
    const float* bq2 = (const float*)d_in[17];
    const float* Wq3 = (const float*)d_in[18];
    const float* bq3 = (const float*)d_in[19];
    float* out = (float*)d_out;

    char* ws = (char*)d_ws;
    size_t off = 0;
    auto carve = [&](size_t bytes) -> void* {
        void* p = ws + off;
        off += (bytes + 255) & ~(size_t)255;
        return p;
    };
    f16*   u1f  = (f16*)carve((size_t)64 * 2 * 16384 * 2);      // 4 MB, 32x32 A-frag order
    f16*   u2   = (f16*)carve((size_t)64 * 64 * 2 * 256 * 2);   // 4 MB, row order
    float* x0   = (float*)carve((size_t)64 * 64 * 24 * 4);
    float* agg  = (float*)carve((size_t)64 * 64 * 256 * 4);     // 4 MB
    f16*   W2f  = (f16*)carve((size_t)2 * 131072 * 2);          // 512 KB, 32x32 B-frag order
    f16*   Wo1f = (f16*)carve((size_t)9 * 16 * 64 * 8 * 2);
    f16*   Wo2f = (f16*)carve((size_t)8 * 16 * 64 * 8 * 2);
    f16*   Wo3f = (f16*)carve((size_t)8 * 2 * 64 * 8 * 2);

    prep_and_u<<<dim3(291), dim3(256), 0, stream>>>(Wm2, Wo1, Wo2, Wo3, W2f, Wo1f, Wo2f, Wo3f,
                                                    data, act, Wm1, bm1, x0, u1f, u2, out);
    edge_kernel<<<dim3(1024), dim3(256), 0, stream>>>(u1f, u2, edges, W2f, bm2, agg);
    out_mlp<<<dim3(256), dim3(256), 0, stream>>>(x0, agg, Wo1f, Wo2f, Wo3f, bo1, bo2, bo3,
                                                 Wq2, bq2, Wq3, bq3, out);
}